// Round 11
// baseline (1221.524 us; speedup 1.0000x reference)
//
#include <hip/hip_runtime.h>
#include <math.h>

#define FIN 512
#define FH  64
#define FO  32

#define BSH    8          // 256 nodes per dst-bucket
#define BNODES 256
#define NCHUNK 256        // radix chunk-blocks
#define NBMAX  512

typedef __bf16 bf16_t;
typedef bf16_t bf16x8 __attribute__((ext_vector_type(8)));
typedef float  f32x4  __attribute__((ext_vector_type(4)));

__device__ __forceinline__ float bf_lo(unsigned u) {
  return __builtin_bit_cast(float, u << 16);
}
__device__ __forceinline__ float bf_hi(unsigned u) {
  return __builtin_bit_cast(float, u & 0xffff0000u);
}

// swizzled LDS index for layer-1 accumulator: row dl, dim d (0..63)
__device__ __forceinline__ int swz(int dl, int d) {
  return (dl << 6) | (d ^ (dl & 31));
}

// fused init: zero deg, build W1T bf16 [64][512], W2T bf16 [32][64]
__global__ __launch_bounds__(256) void k_init(int* __restrict__ p, int n2,
                                              const float* __restrict__ W1,
                                              bf16_t* __restrict__ w1t,
                                              const float* __restrict__ W2,
                                              bf16_t* __restrict__ w2t) {
  int i = blockIdx.x * 256 + threadIdx.x;
  if (i < n2) p[i] = 0;
  if (i < FIN * FH) {
    int c = i >> 9, k = i & 511;
    w1t[i] = (bf16_t)W1[(size_t)k * FH + c];
  }
  if (i < FH * FO) {
    int c = i >> 6, k = i & 63;
    w2t[i] = (bf16_t)W2[(size_t)k * FO + c];
  }
}

// radix pass A: per-chunk bucket histogram (LDS) + global deg histogram
__global__ __launch_bounds__(256) void k_histA(const int* __restrict__ dst,
                                               int* __restrict__ deg,
                                               int* __restrict__ histmat,
                                               int E, int NB) {
  __shared__ int lh[NBMAX];
  int t = threadIdx.x;
  int g = blockIdx.x;
  for (int i = t; i < NB; i += 256) lh[i] = 0;
  __syncthreads();
  int C = (E + NCHUNK - 1) / NCHUNK;
  int e0 = g * C, e1 = min(E, e0 + C);
  for (int e = e0 + t; e < e1; e += 256) {
    int d = dst[e];
    atomicAdd(&deg[d], 1);
    atomicAdd(&lh[d >> BSH], 1);
  }
  __syncthreads();
  for (int b = t; b < NB; b += 256) histmat[(size_t)b * NCHUNK + g] = lh[b];
}

// fused: blocks [0,nb) dinv from deg; blocks [nb,nb+NB) per-bucket chunk-scan
__global__ __launch_bounds__(256) void k_dinvS1(const int* __restrict__ deg,
                                                float* __restrict__ dinv,
                                                const int* __restrict__ histmat,
                                                int* __restrict__ rowscan,
                                                int* __restrict__ rowsum,
                                                int n, int nb, int NB) {
  __shared__ int s[NCHUNK];
  int blk = blockIdx.x, t = threadIdx.x;
  if (blk < nb) {
    int i = blk * 256 + t;
    if (i < n) dinv[i] = rsqrtf((float)(deg[i] + 1));
  } else {
    int b = blk - nb;
    int v = histmat[(size_t)b * NCHUNK + t];
    s[t] = v;
    __syncthreads();
    #pragma unroll
    for (int off = 1; off < NCHUNK; off <<= 1) {
      int tmp = (t >= off) ? s[t - off] : 0;
      __syncthreads();
      s[t] += tmp;
      __syncthreads();
    }
    rowscan[(size_t)b * NCHUNK + t] = s[t] - v;
    if (t == 255) rowsum[b] = s[255];
  }
}

// exclusive scan of per-bucket totals -> bbase[0..NB], bbase[NB]=E
__global__ __launch_bounds__(256) void k_S2(const int* __restrict__ rowsum,
                                            int* __restrict__ bbase, int NB, int E) {
  __shared__ int s[256];
  int t = threadIdx.x;
  int carry = 0;
  for (int base = 0; base < NB; base += 256) {
    int idx = base + t;
    int v = (idx < NB) ? rowsum[idx] : 0;
    s[t] = v;
    __syncthreads();
    #pragma unroll
    for (int off = 1; off < 256; off <<= 1) {
      int tmp = (t >= off) ? s[t - off] : 0;
      __syncthreads();
      s[t] += tmp;
      __syncthreads();
    }
    if (idx < NB) bbase[idx] = s[t] - v + carry;
    carry += s[255];
    __syncthreads();
  }
  if (t == 0) bbase[NB] = E;
}

// scatter packed (dlocal<<24 | src) into bucket-grouped part[]
__global__ __launch_bounds__(256) void k_scatC(const int* __restrict__ ei,
                                               const int* __restrict__ rowscan,
                                               const int* __restrict__ bbase,
                                               unsigned* __restrict__ part,
                                               int E, int NB) {
  __shared__ int lcur[NBMAX];
  int t = threadIdx.x;
  int g = blockIdx.x;
  for (int b = t; b < NB; b += 256) lcur[b] = rowscan[(size_t)b * NCHUNK + g] + bbase[b];
  __syncthreads();
  int C = (E + NCHUNK - 1) / NCHUNK;
  int e0 = g * C, e1 = min(E, e0 + C);
  for (int e = e0 + t; e < e1; e += 256) {
    int s = ei[e];
    int d = ei[E + e];
    int b = d >> BSH;
    int pos = atomicAdd(&lcur[b], 1);
    part[pos] = (unsigned)s | ((unsigned)(d & (BNODES - 1)) << 24);
  }
}

// GEMM1 via MFMA: P1[n][64] (bf16) = dinv[n] * (x[n] @ W1). x-read-BW bound.
__global__ __launch_bounds__(256) void k_gemm1(const float* __restrict__ x,
                                               const bf16_t* __restrict__ w1t,
                                               const float* __restrict__ dinv,
                                               bf16_t* __restrict__ P1, int n) {
  int t = threadIdx.x;
  int w = t >> 6, l = t & 63;
  int rowBase = blockIdx.x * 64 + w * 16;
  int fr = l & 15, fk = l >> 4;
  int ar = rowBase + fr; if (ar >= n) ar = n - 1;
  const float* xp = x + (size_t)ar * FIN + fk * 8;
  const bf16_t* wb = w1t + (size_t)fr * FIN + fk * 8;

  f32x4 acc0 = {0.f, 0.f, 0.f, 0.f};
  f32x4 acc1 = {0.f, 0.f, 0.f, 0.f};
  f32x4 acc2 = {0.f, 0.f, 0.f, 0.f};
  f32x4 acc3 = {0.f, 0.f, 0.f, 0.f};

  #pragma unroll 4
  for (int kt = 0; kt < FIN; kt += 32) {
    float4 a0 = *(const float4*)(xp + kt);
    float4 a1 = *(const float4*)(xp + kt + 4);
    bf16x8 av;
    av[0] = (bf16_t)a0.x; av[1] = (bf16_t)a0.y; av[2] = (bf16_t)a0.z; av[3] = (bf16_t)a0.w;
    av[4] = (bf16_t)a1.x; av[5] = (bf16_t)a1.y; av[6] = (bf16_t)a1.z; av[7] = (bf16_t)a1.w;
    bf16x8 b0 = *(const bf16x8*)(wb + kt);
    bf16x8 b1 = *(const bf16x8*)(wb + (size_t)16 * FIN + kt);
    bf16x8 b2 = *(const bf16x8*)(wb + (size_t)32 * FIN + kt);
    bf16x8 b3 = *(const bf16x8*)(wb + (size_t)48 * FIN + kt);
    acc0 = __builtin_amdgcn_mfma_f32_16x16x32_bf16(av, b0, acc0, 0, 0, 0);
    acc1 = __builtin_amdgcn_mfma_f32_16x16x32_bf16(av, b1, acc1, 0, 0, 0);
    acc2 = __builtin_amdgcn_mfma_f32_16x16x32_bf16(av, b2, acc2, 0, 0, 0);
    acc3 = __builtin_amdgcn_mfma_f32_16x16x32_bf16(av, b3, acc3, 0, 0, 0);
  }

  #pragma unroll
  for (int rg = 0; rg < 4; rg++) {
    int grow = rowBase + fk * 4 + rg;
    if (grow < n) {
      float dv = dinv[grow];
      bf16_t* prow = P1 + (size_t)grow * FH + fr;
      prow[0]  = (bf16_t)(dv * acc0[rg]);
      prow[16] = (bf16_t)(dv * acc1[rg]);
      prow[32] = (bf16_t)(dv * acc2[rg]);
      prow[48] = (bf16_t)(dv * acc3[rg]);
    }
  }
}

// layer-1 bucket gather: stream part slice, LDS fp32 accumulate, fused relu/bias -> h
__global__ __launch_bounds__(512) void k_gAcc1(const bf16_t* __restrict__ P1,
                                               const unsigned* __restrict__ part,
                                               const int* __restrict__ bbase,
                                               const float* __restrict__ dinv,
                                               const float* __restrict__ b1,
                                               bf16_t* __restrict__ h, int n) {
  __shared__ float acc[BNODES * 64];  // 64 KB, XOR-swizzled rows
  int b = blockIdx.x, t = threadIdx.x;
  int base = b << BSH;
  const uint4* P1v = (const uint4*)P1;
  int ln = t & 7;          // 16B lane within row
  int nl0 = t >> 3;        // node for init/epilogue (64 per pass)

  // init with self-loop row (fp32)
  #pragma unroll
  for (int p = 0; p < 4; p++) {
    int nl = nl0 + p * 64;
    int v = base + nl;
    float vl[8] = {0.f, 0.f, 0.f, 0.f, 0.f, 0.f, 0.f, 0.f};
    if (v < n) {
      uint4 r = P1v[(size_t)v * 8 + ln];
      vl[0] = bf_lo(r.x); vl[1] = bf_hi(r.x); vl[2] = bf_lo(r.y); vl[3] = bf_hi(r.y);
      vl[4] = bf_lo(r.z); vl[5] = bf_hi(r.z); vl[6] = bf_lo(r.w); vl[7] = bf_hi(r.w);
    }
    #pragma unroll
    for (int k = 0; k < 8; k++) acc[swz(nl, ln * 8 + k)] = vl[k];
  }
  __syncthreads();

  int start = bbase[b], end = bbase[b + 1];
  int sg = t >> 3;         // 64 subgroups of 8 lanes
  int j = start + sg;
  for (; j + 64 < end; j += 128) {
    unsigned pk0 = part[j];
    unsigned pk1 = part[j + 64];
    uint4 r0 = P1v[(size_t)(pk0 & 0xFFFFFFu) * 8 + ln];
    uint4 r1 = P1v[(size_t)(pk1 & 0xFFFFFFu) * 8 + ln];
    int dl0 = (int)(pk0 >> 24), dl1 = (int)(pk1 >> 24);
    atomicAdd(&acc[swz(dl0, ln * 8 + 0)], bf_lo(r0.x));
    atomicAdd(&acc[swz(dl0, ln * 8 + 1)], bf_hi(r0.x));
    atomicAdd(&acc[swz(dl0, ln * 8 + 2)], bf_lo(r0.y));
    atomicAdd(&acc[swz(dl0, ln * 8 + 3)], bf_hi(r0.y));
    atomicAdd(&acc[swz(dl0, ln * 8 + 4)], bf_lo(r0.z));
    atomicAdd(&acc[swz(dl0, ln * 8 + 5)], bf_hi(r0.z));
    atomicAdd(&acc[swz(dl0, ln * 8 + 6)], bf_lo(r0.w));
    atomicAdd(&acc[swz(dl0, ln * 8 + 7)], bf_hi(r0.w));
    atomicAdd(&acc[swz(dl1, ln * 8 + 0)], bf_lo(r1.x));
    atomicAdd(&acc[swz(dl1, ln * 8 + 1)], bf_hi(r1.x));
    atomicAdd(&acc[swz(dl1, ln * 8 + 2)], bf_lo(r1.y));
    atomicAdd(&acc[swz(dl1, ln * 8 + 3)], bf_hi(r1.y));
    atomicAdd(&acc[swz(dl1, ln * 8 + 4)], bf_lo(r1.z));
    atomicAdd(&acc[swz(dl1, ln * 8 + 5)], bf_hi(r1.z));
    atomicAdd(&acc[swz(dl1, ln * 8 + 6)], bf_lo(r1.w));
    atomicAdd(&acc[swz(dl1, ln * 8 + 7)], bf_hi(r1.w));
  }
  if (j < end) {
    unsigned pk = part[j];
    uint4 r = P1v[(size_t)(pk & 0xFFFFFFu) * 8 + ln];
    int dl = (int)(pk >> 24);
    atomicAdd(&acc[swz(dl, ln * 8 + 0)], bf_lo(r.x));
    atomicAdd(&acc[swz(dl, ln * 8 + 1)], bf_hi(r.x));
    atomicAdd(&acc[swz(dl, ln * 8 + 2)], bf_lo(r.y));
    atomicAdd(&acc[swz(dl, ln * 8 + 3)], bf_hi(r.y));
    atomicAdd(&acc[swz(dl, ln * 8 + 4)], bf_lo(r.z));
    atomicAdd(&acc[swz(dl, ln * 8 + 5)], bf_hi(r.z));
    atomicAdd(&acc[swz(dl, ln * 8 + 6)], bf_lo(r.w));
    atomicAdd(&acc[swz(dl, ln * 8 + 7)], bf_hi(r.w));
  }
  __syncthreads();

  // epilogue: h = relu(dinv*acc + b1) -> bf16
  float4 bb0 = ((const float4*)b1)[ln * 2];
  float4 bb1 = ((const float4*)b1)[ln * 2 + 1];
  #pragma unroll
  for (int p = 0; p < 4; p++) {
    int nl = nl0 + p * 64;
    int v = base + nl;
    if (v < n) {
      float dv = dinv[v];
      float a0 = acc[swz(nl, ln * 8 + 0)];
      float a1 = acc[swz(nl, ln * 8 + 1)];
      float a2 = acc[swz(nl, ln * 8 + 2)];
      float a3 = acc[swz(nl, ln * 8 + 3)];
      float a4 = acc[swz(nl, ln * 8 + 4)];
      float a5 = acc[swz(nl, ln * 8 + 5)];
      float a6 = acc[swz(nl, ln * 8 + 6)];
      float a7 = acc[swz(nl, ln * 8 + 7)];
      bf16x8 hv;
      hv[0] = (bf16_t)fmaxf(dv * a0 + bb0.x, 0.f);
      hv[1] = (bf16_t)fmaxf(dv * a1 + bb0.y, 0.f);
      hv[2] = (bf16_t)fmaxf(dv * a2 + bb0.z, 0.f);
      hv[3] = (bf16_t)fmaxf(dv * a3 + bb0.w, 0.f);
      hv[4] = (bf16_t)fmaxf(dv * a4 + bb1.x, 0.f);
      hv[5] = (bf16_t)fmaxf(dv * a5 + bb1.y, 0.f);
      hv[6] = (bf16_t)fmaxf(dv * a6 + bb1.z, 0.f);
      hv[7] = (bf16_t)fmaxf(dv * a7 + bb1.w, 0.f);
      ((bf16x8*)h)[(size_t)v * 8 + ln] = hv;
    }
  }
}

// GEMM2 via MFMA: P2[n][32] (bf16) = dinv[n] * (h[n] @ W2)
__global__ __launch_bounds__(256) void k_gemm2(const bf16_t* __restrict__ h,
                                               const bf16_t* __restrict__ w2t,
                                               const float* __restrict__ dinv,
                                               bf16_t* __restrict__ P2, int n) {
  int t = threadIdx.x;
  int w = t >> 6, l = t & 63;
  int rowBase = blockIdx.x * 64 + w * 16;
  int fr = l & 15, fk = l >> 4;
  int ar = rowBase + fr; if (ar >= n) ar = n - 1;
  const bf16_t* hp = h + (size_t)ar * FH + fk * 8;
  const bf16_t* wb0 = w2t + (size_t)fr * FH + fk * 8;
  const bf16_t* wb1 = w2t + (size_t)(fr + 16) * FH + fk * 8;

  f32x4 acc0 = {0.f, 0.f, 0.f, 0.f};
  f32x4 acc1 = {0.f, 0.f, 0.f, 0.f};
  #pragma unroll
  for (int kt = 0; kt < FH; kt += 32) {
    bf16x8 af = *(const bf16x8*)(hp + kt);
    bf16x8 b0 = *(const bf16x8*)(wb0 + kt);
    bf16x8 b1 = *(const bf16x8*)(wb1 + kt);
    acc0 = __builtin_amdgcn_mfma_f32_16x16x32_bf16(af, b0, acc0, 0, 0, 0);
    acc1 = __builtin_amdgcn_mfma_f32_16x16x32_bf16(af, b1, acc1, 0, 0, 0);
  }
  #pragma unroll
  for (int rg = 0; rg < 4; rg++) {
    int grow = rowBase + fk * 4 + rg;
    if (grow < n) {
      float dv = dinv[grow];
      P2[(size_t)grow * FO + fr]      = (bf16_t)(dv * acc0[rg]);
      P2[(size_t)grow * FO + fr + 16] = (bf16_t)(dv * acc1[rg]);
    }
  }
}

// layer-2 bucket gather + bias + log_softmax -> out
__global__ __launch_bounds__(512) void k_gAcc2(const bf16_t* __restrict__ P2,
                                               const unsigned* __restrict__ part,
                                               const int* __restrict__ bbase,
                                               const float* __restrict__ dinv,
                                               const float* __restrict__ b2,
                                               float* __restrict__ out, int n) {
  __shared__ float acc[BNODES][33];  // pad 33 breaks bank alias
  int b = blockIdx.x, t = threadIdx.x;
  int base = b << BSH;
  const uint4* P2v = (const uint4*)P2;
  int ln = t & 3;          // 16B lane within 64B row
  int nl0 = t >> 2;        // node for init/epilogue (128 per pass)

  #pragma unroll
  for (int p = 0; p < 2; p++) {
    int nl = nl0 + p * 128;
    int v = base + nl;
    float vl[8] = {0.f, 0.f, 0.f, 0.f, 0.f, 0.f, 0.f, 0.f};
    if (v < n) {
      uint4 r = P2v[(size_t)v * 4 + ln];
      vl[0] = bf_lo(r.x); vl[1] = bf_hi(r.x); vl[2] = bf_lo(r.y); vl[3] = bf_hi(r.y);
      vl[4] = bf_lo(r.z); vl[5] = bf_hi(r.z); vl[6] = bf_lo(r.w); vl[7] = bf_hi(r.w);
    }
    float* a = &acc[nl][ln * 8];
    #pragma unroll
    for (int k = 0; k < 8; k++) a[k] = vl[k];
  }
  __syncthreads();

  int start = bbase[b], end = bbase[b + 1];
  int sg = t >> 2;         // 128 subgroups of 4 lanes
  int j = start + sg;
  for (; j + 128 < end; j += 256) {
    unsigned pk0 = part[j];
    unsigned pk1 = part[j + 128];
    uint4 r0 = P2v[(size_t)(pk0 & 0xFFFFFFu) * 4 + ln];
    uint4 r1 = P2v[(size_t)(pk1 & 0xFFFFFFu) * 4 + ln];
    float* a0 = &acc[pk0 >> 24][ln * 8];
    atomicAdd(a0 + 0, bf_lo(r0.x)); atomicAdd(a0 + 1, bf_hi(r0.x));
    atomicAdd(a0 + 2, bf_lo(r0.y)); atomicAdd(a0 + 3, bf_hi(r0.y));
    atomicAdd(a0 + 4, bf_lo(r0.z)); atomicAdd(a0 + 5, bf_hi(r0.z));
    atomicAdd(a0 + 6, bf_lo(r0.w)); atomicAdd(a0 + 7, bf_hi(r0.w));
    float* a1 = &acc[pk1 >> 24][ln * 8];
    atomicAdd(a1 + 0, bf_lo(r1.x)); atomicAdd(a1 + 1, bf_hi(r1.x));
    atomicAdd(a1 + 2, bf_lo(r1.y)); atomicAdd(a1 + 3, bf_hi(r1.y));
    atomicAdd(a1 + 4, bf_lo(r1.z)); atomicAdd(a1 + 5, bf_hi(r1.z));
    atomicAdd(a1 + 6, bf_lo(r1.w)); atomicAdd(a1 + 7, bf_hi(r1.w));
  }
  if (j < end) {
    unsigned pk = part[j];
    uint4 r = P2v[(size_t)(pk & 0xFFFFFFu) * 4 + ln];
    float* a = &acc[pk >> 24][ln * 8];
    atomicAdd(a + 0, bf_lo(r.x)); atomicAdd(a + 1, bf_hi(r.x));
    atomicAdd(a + 2, bf_lo(r.y)); atomicAdd(a + 3, bf_hi(r.y));
    atomicAdd(a + 4, bf_lo(r.z)); atomicAdd(a + 5, bf_hi(r.z));
    atomicAdd(a + 6, bf_lo(r.w)); atomicAdd(a + 7, bf_hi(r.w));
  }
  __syncthreads();

  // epilogue: bias + log_softmax over 32 dims (4-lane group reduce)
  float4 bb0 = ((const float4*)b2)[ln * 2];
  float4 bb1 = ((const float4*)b2)[ln * 2 + 1];
  #pragma unroll
  for (int p = 0; p < 2; p++) {
    int nl = nl0 + p * 128;
    int v = base + nl;
    if (v < n) {
      float dv = dinv[v];
      float* a = &acc[nl][ln * 8];
      float val[8];
      val[0] = dv * a[0] + bb0.x; val[1] = dv * a[1] + bb0.y;
      val[2] = dv * a[2] + bb0.z; val[3] = dv * a[3] + bb0.w;
      val[4] = dv * a[4] + bb1.x; val[5] = dv * a[5] + bb1.y;
      val[6] = dv * a[6] + bb1.z; val[7] = dv * a[7] + bb1.w;
      float m = val[0];
      #pragma unroll
      for (int q = 1; q < 8; q++) m = fmaxf(m, val[q]);
      m = fmaxf(m, __shfl_xor(m, 1, 64));
      m = fmaxf(m, __shfl_xor(m, 2, 64));
      float se = 0.f;
      #pragma unroll
      for (int q = 0; q < 8; q++) se += expf(val[q] - m);
      se += __shfl_xor(se, 1, 64);
      se += __shfl_xor(se, 2, 64);
      float lse = m + logf(se);
      float4 o0, o1;
      o0.x = val[0] - lse; o0.y = val[1] - lse; o0.z = val[2] - lse; o0.w = val[3] - lse;
      o1.x = val[4] - lse; o1.y = val[5] - lse; o1.z = val[6] - lse; o1.w = val[7] - lse;
      float* orow = out + (size_t)v * FO + ln * 8;
      *(float4*)orow = o0;
      *(float4*)(orow + 4) = o1;
    }
  }
}

extern "C" void kernel_launch(void* const* d_in, const int* in_sizes, int n_in,
                              void* d_out, int out_size, void* d_ws, size_t ws_size,
                              hipStream_t stream) {
  const float* x  = (const float*)d_in[0];
  const int*   ei = (const int*)d_in[1];
  const float* W1 = (const float*)d_in[2];
  const float* b1 = (const float*)d_in[3];
  const float* W2 = (const float*)d_in[4];
  const float* b2 = (const float*)d_in[5];
  const int N = in_sizes[0] / FIN;
  const int E = in_sizes[1] / 2;
  float* out = (float*)d_out;

  size_t NP = ((size_t)N + 63) & ~(size_t)63;
  size_t EP = ((size_t)E + 63) & ~(size_t)63;
  int nb = (N + 255) / 256;
  int NB = (N + BNODES - 1) >> BSH;   // dst-buckets of 256 nodes

  int*      deg     = (int*)d_ws;                        // NP
  float*    dinv    = (float*)(deg + NP);                // NP
  int*      histmat = (int*)(dinv + NP);                 // NBMAX*NCHUNK
  int*      rowscan = histmat + (size_t)NBMAX * NCHUNK;  // NBMAX*NCHUNK
  int*      rowsum  = rowscan + (size_t)NBMAX * NCHUNK;  // NBMAX
  int*      bbase   = rowsum + NBMAX;                    // NBMAX+1
  unsigned* part    = (unsigned*)(bbase + NBMAX + 64);   // EP
  bf16_t*   w1t     = (bf16_t*)(part + EP);              // 64*512
  bf16_t*   w2t     = w1t + (size_t)FH * FIN;            // 32*64
  bf16_t*   P1      = w2t + (size_t)FO * FH;             // NP*64
  bf16_t*   h       = P1 + NP * FH;                      // NP*64
  bf16_t*   P2      = h + NP * FH;                       // NP*32

  int initN = (int)NP;
  if (initN < FIN * FH) initN = FIN * FH;
  k_init<<<(initN + 255) / 256, 256, 0, stream>>>(deg, (int)NP, W1, w1t, W2, w2t);
  k_histA<<<NCHUNK, 256, 0, stream>>>(ei + E, deg, histmat, E, NB);
  k_dinvS1<<<nb + NB, 256, 0, stream>>>(deg, dinv, histmat, rowscan, rowsum, N, nb, NB);
  k_S2<<<1, 256, 0, stream>>>(rowsum, bbase, NB, E);
  k_scatC<<<NCHUNK, 256, 0, stream>>>(ei, rowscan, bbase, part, E, NB);
  k_gemm1<<<(N + 63) / 64, 256, 0, stream>>>(x, w1t, dinv, P1, N);
  k_gAcc1<<<NB, 512, 0, stream>>>(P1, part, bbase, dinv, b1, h, N);
  k_gemm2<<<(N + 63) / 64, 256, 0, stream>>>(h, w2t, dinv, P2, N);
  k_gAcc2<<<NB, 512, 0, stream>>>(P2, part, bbase, dinv, b2, out, N);
}

// Round 12
// 203.087 us; speedup vs baseline: 6.0148x; 6.0148x over previous
//
#include <hip/hip_runtime.h>
#include <math.h>

#define FIN 512
#define FH  64
#define FO  32

#define BSH    9          // 512 nodes per dst-bucket
#define BNODES 512
#define NCHUNK 256        // radix chunk-blocks
#define BCAP   10240     // LDS csr capacity per bucket (mean 8192, sigma ~90)
#define NBMAX  512

typedef __bf16 bf16_t;
typedef bf16_t bf16x8 __attribute__((ext_vector_type(8)));
typedef float  f32x4  __attribute__((ext_vector_type(4)));

__device__ __forceinline__ float bf_lo(unsigned u) {
  return __builtin_bit_cast(float, u << 16);
}
__device__ __forceinline__ float bf_hi(unsigned u) {
  return __builtin_bit_cast(float, u & 0xffff0000u);
}

// init: convert weights only (nothing else needs zeroing)
__global__ __launch_bounds__(256) void k_init(const float* __restrict__ W1,
                                              bf16_t* __restrict__ w1t,
                                              const float* __restrict__ W2,
                                              bf16_t* __restrict__ w2t) {
  int i = blockIdx.x * 256 + threadIdx.x;
  if (i < FIN * FH) {
    int c = i >> 9, k = i & 511;
    w1t[i] = (bf16_t)W1[(size_t)k * FH + c];
  }
  if (i < FH * FO) {
    int c = i >> 6, k = i & 63;
    w2t[i] = (bf16_t)W2[(size_t)k * FO + c];
  }
}

// radix pass A: per-chunk bucket histogram (pure LDS, no global atomics)
__global__ __launch_bounds__(256) void k_histA(const int* __restrict__ dst,
                                               int* __restrict__ histmat,
                                               int E, int NB) {
  __shared__ int lh[NBMAX];
  int t = threadIdx.x;
  int g = blockIdx.x;
  for (int i = t; i < NB; i += 256) lh[i] = 0;
  __syncthreads();
  int C = (E + NCHUNK - 1) / NCHUNK;
  int e0 = g * C, e1 = min(E, e0 + C);
  for (int e = e0 + t; e < e1; e += 256) {
    atomicAdd(&lh[dst[e] >> BSH], 1);
  }
  __syncthreads();
  for (int b = t; b < NB; b += 256) histmat[(size_t)b * NCHUNK + g] = lh[b];
}

// radix pass B: per-bucket exclusive scan over chunks -> rowscan, total -> rowsum
__global__ __launch_bounds__(256) void k_scanB(const int* __restrict__ histmat,
                                               int* __restrict__ rowscan,
                                               int* __restrict__ rowsum, int NB) {
  __shared__ int s[NCHUNK];
  int b = blockIdx.x;
  int t = threadIdx.x;
  int v = histmat[(size_t)b * NCHUNK + t];
  s[t] = v;
  __syncthreads();
  #pragma unroll
  for (int off = 1; off < NCHUNK; off <<= 1) {
    int tmp = (t >= off) ? s[t - off] : 0;
    __syncthreads();
    s[t] += tmp;
    __syncthreads();
  }
  rowscan[(size_t)b * NCHUNK + t] = s[t] - v;
  if (t == 255) rowsum[b] = s[255];
}

// radix pass C: scatter packed (dlocal<<23 | src) into bucket-grouped part[]
// bucket bases derived locally by scanning rowsum (NB <= 512, trivial)
__global__ __launch_bounds__(256) void k_scatC(const int* __restrict__ ei,
                                               const int* __restrict__ rowscan,
                                               const int* __restrict__ rowsum,
                                               unsigned* __restrict__ part,
                                               int E, int NB) {
  __shared__ int lcur[NBMAX];
  __shared__ int sc[256];
  int t = threadIdx.x;
  int g = blockIdx.x;
  int carry = 0;
  for (int bb = 0; bb < NB; bb += 256) {
    int idx = bb + t;
    int v = (idx < NB) ? rowsum[idx] : 0;
    sc[t] = v;
    __syncthreads();
    #pragma unroll
    for (int off = 1; off < 256; off <<= 1) {
      int tmp = (t >= off) ? sc[t - off] : 0;
      __syncthreads();
      sc[t] += tmp;
      __syncthreads();
    }
    if (idx < NB) lcur[idx] = sc[t] - v + carry + rowscan[(size_t)idx * NCHUNK + g];
    carry += sc[255];
    __syncthreads();
  }
  __syncthreads();
  int C = (E + NCHUNK - 1) / NCHUNK;
  int e0 = g * C, e1 = min(E, e0 + C);
  for (int e = e0 + t; e < e1; e += 256) {
    int s = ei[e];
    int d = ei[E + e];
    int b = d >> BSH;
    int pos = atomicAdd(&lcur[b], 1);
    part[pos] = (unsigned)s | ((unsigned)(d & (BNODES - 1)) << 23);
  }
}

// per-bucket CSR build: local node histogram + scan (no global rowoff input);
// WRITES csr (node-sorted), rowoff[v], dinv[v].
__global__ __launch_bounds__(256) void k_csrb(const unsigned* __restrict__ part,
                                              const int* __restrict__ rowsum,
                                              int* __restrict__ csr,
                                              int* __restrict__ rowoff,
                                              float* __restrict__ dinv,
                                              int n, int NB) {
  __shared__ int sc[256];
  __shared__ int lhist[BNODES];
  __shared__ int lro[BNODES];
  __shared__ int lcur[BNODES];
  __shared__ int lcsr[BCAP];
  int b = blockIdx.x;
  int t = threadIdx.x;
  int base = b << BSH;

  // bo = sum(rowsum[0..b)) via block reduce of strided partials
  int partial = 0;
  for (int i = t; i < b; i += 256) partial += rowsum[i];
  sc[t] = partial;
  __syncthreads();
  #pragma unroll
  for (int off = 128; off > 0; off >>= 1) {
    if (t < off) sc[t] += sc[t + off];
    __syncthreads();
  }
  int bo = sc[0];
  int cnt = rowsum[b];
  __syncthreads();

  // local node histogram
  for (int i = t; i < BNODES; i += 256) lhist[i] = 0;
  __syncthreads();
  const unsigned* pp = part + bo;
  for (int j = t; j < cnt; j += 256) atomicAdd(&lhist[pp[j] >> 23], 1);
  __syncthreads();

  // exclusive scan of lhist[0..511] -> lro (two 256 rounds)
  int v0 = lhist[t];
  sc[t] = v0;
  __syncthreads();
  #pragma unroll
  for (int off = 1; off < 256; off <<= 1) {
    int tmp = (t >= off) ? sc[t - off] : 0;
    __syncthreads();
    sc[t] += tmp;
    __syncthreads();
  }
  lro[t] = sc[t] - v0;
  int tot0 = sc[255];
  __syncthreads();
  int v1 = lhist[256 + t];
  sc[t] = v1;
  __syncthreads();
  #pragma unroll
  for (int off = 1; off < 256; off <<= 1) {
    int tmp = (t >= off) ? sc[t - off] : 0;
    __syncthreads();
    sc[t] += tmp;
    __syncthreads();
  }
  lro[256 + t] = sc[t] - v1 + tot0;
  __syncthreads();

  // write rowoff + dinv; zero cursors
  for (int i = t; i < BNODES; i += 256) {
    int v = base + i;
    if (v < n) {
      rowoff[v] = bo + lro[i];
      dinv[v] = rsqrtf((float)(lhist[i] + 1));
    }
    lcur[i] = 0;
  }
  if (t == 0 && base + BNODES >= n) rowoff[n] = bo + cnt;
  __syncthreads();

  // node-sort into LDS, dump coalesced
  if (cnt <= BCAP) {
    for (int j = t; j < cnt; j += 256) {
      unsigned pk = pp[j];
      int dl = (int)(pk >> 23);
      int pos = atomicAdd(&lcur[dl], 1);
      lcsr[lro[dl] + pos] = (int)(pk & 0x7FFFFFu);
    }
    __syncthreads();
    for (int j = t; j < cnt; j += 256) csr[bo + j] = lcsr[j];
  } else {  // statistical impossibility; correctness fallback
    for (int j = t; j < cnt; j += 256) {
      unsigned pk = pp[j];
      int dl = (int)(pk >> 23);
      int pos = atomicAdd(&lcur[dl], 1);
      csr[bo + lro[dl] + pos] = (int)(pk & 0x7FFFFFu);
    }
  }
}

// GEMM1 via MFMA: P1[n][64] (bf16) = dinv[n] * (x[n] @ W1). x-read-BW bound.
__global__ __launch_bounds__(256) void k_gemm1(const float* __restrict__ x,
                                               const bf16_t* __restrict__ w1t,
                                               const float* __restrict__ dinv,
                                               bf16_t* __restrict__ P1, int n) {
  int t = threadIdx.x;
  int w = t >> 6, l = t & 63;
  int rowBase = blockIdx.x * 64 + w * 16;
  int fr = l & 15, fk = l >> 4;
  int ar = rowBase + fr; if (ar >= n) ar = n - 1;
  const float* xp = x + (size_t)ar * FIN + fk * 8;
  const bf16_t* wb = w1t + (size_t)fr * FIN + fk * 8;

  f32x4 acc0 = {0.f, 0.f, 0.f, 0.f};
  f32x4 acc1 = {0.f, 0.f, 0.f, 0.f};
  f32x4 acc2 = {0.f, 0.f, 0.f, 0.f};
  f32x4 acc3 = {0.f, 0.f, 0.f, 0.f};

  #pragma unroll 4
  for (int kt = 0; kt < FIN; kt += 32) {
    float4 a0 = *(const float4*)(xp + kt);
    float4 a1 = *(const float4*)(xp + kt + 4);
    bf16x8 av;
    av[0] = (bf16_t)a0.x; av[1] = (bf16_t)a0.y; av[2] = (bf16_t)a0.z; av[3] = (bf16_t)a0.w;
    av[4] = (bf16_t)a1.x; av[5] = (bf16_t)a1.y; av[6] = (bf16_t)a1.z; av[7] = (bf16_t)a1.w;
    bf16x8 b0 = *(const bf16x8*)(wb + kt);
    bf16x8 b1 = *(const bf16x8*)(wb + (size_t)16 * FIN + kt);
    bf16x8 b2 = *(const bf16x8*)(wb + (size_t)32 * FIN + kt);
    bf16x8 b3 = *(const bf16x8*)(wb + (size_t)48 * FIN + kt);
    acc0 = __builtin_amdgcn_mfma_f32_16x16x32_bf16(av, b0, acc0, 0, 0, 0);
    acc1 = __builtin_amdgcn_mfma_f32_16x16x32_bf16(av, b1, acc1, 0, 0, 0);
    acc2 = __builtin_amdgcn_mfma_f32_16x16x32_bf16(av, b2, acc2, 0, 0, 0);
    acc3 = __builtin_amdgcn_mfma_f32_16x16x32_bf16(av, b3, acc3, 0, 0, 0);
  }

  #pragma unroll
  for (int rg = 0; rg < 4; rg++) {
    int grow = rowBase + fk * 4 + rg;
    if (grow < n) {
      float dv = dinv[grow];
      bf16_t* prow = P1 + (size_t)grow * FH + fr;
      prow[0]  = (bf16_t)(dv * acc0[rg]);
      prow[16] = (bf16_t)(dv * acc1[rg]);
      prow[32] = (bf16_t)(dv * acc2[rg]);
      prow[48] = (bf16_t)(dv * acc3[rg]);
    }
  }
}

// gather1: wave = 8 subgroups x 8 lanes x uint4 (16B); one node per subgroup.
__global__ __launch_bounds__(256) void k_gather1(const bf16_t* __restrict__ P1,
                                                 const int* __restrict__ csr,
                                                 const int* __restrict__ rowoff,
                                                 const float* __restrict__ dinv,
                                                 const float* __restrict__ b1,
                                                 bf16_t* __restrict__ h, int n) {
  int l = threadIdx.x & 63;
  int sg = l >> 3, dg = l & 7;
  int wv = (blockIdx.x * 256 + threadIdx.x) >> 6;
  int v = wv * 8 + sg;
  if (v >= n) return;
  const uint4* P1v = (const uint4*)P1;
  int base = rowoff[v];
  int cnt = rowoff[v + 1] - base;
  uint4 sv = P1v[(size_t)v * 8 + dg];  // self loop
  float a0 = bf_lo(sv.x), a1 = bf_hi(sv.x), a2 = bf_lo(sv.y), a3 = bf_hi(sv.y);
  float a4 = bf_lo(sv.z), a5 = bf_hi(sv.z), a6 = bf_lo(sv.w), a7 = bf_hi(sv.w);
  float c0 = 0.f, c1 = 0.f, c2 = 0.f, c3 = 0.f, c4 = 0.f, c5 = 0.f, c6 = 0.f, c7 = 0.f;
  int cnt4 = cnt & ~3;
  int j = 0;
  for (; j < cnt4; j += 4) {
    int u0 = csr[base + j];
    int u1 = csr[base + j + 1];
    int u2 = csr[base + j + 2];
    int u3 = csr[base + j + 3];
    uint4 r0 = P1v[(size_t)u0 * 8 + dg];
    uint4 r1 = P1v[(size_t)u1 * 8 + dg];
    uint4 r2 = P1v[(size_t)u2 * 8 + dg];
    uint4 r3 = P1v[(size_t)u3 * 8 + dg];
    a0 += bf_lo(r0.x); a1 += bf_hi(r0.x); a2 += bf_lo(r0.y); a3 += bf_hi(r0.y);
    a4 += bf_lo(r0.z); a5 += bf_hi(r0.z); a6 += bf_lo(r0.w); a7 += bf_hi(r0.w);
    c0 += bf_lo(r1.x); c1 += bf_hi(r1.x); c2 += bf_lo(r1.y); c3 += bf_hi(r1.y);
    c4 += bf_lo(r1.z); c5 += bf_hi(r1.z); c6 += bf_lo(r1.w); c7 += bf_hi(r1.w);
    a0 += bf_lo(r2.x); a1 += bf_hi(r2.x); a2 += bf_lo(r2.y); a3 += bf_hi(r2.y);
    a4 += bf_lo(r2.z); a5 += bf_hi(r2.z); a6 += bf_lo(r2.w); a7 += bf_hi(r2.w);
    c0 += bf_lo(r3.x); c1 += bf_hi(r3.x); c2 += bf_lo(r3.y); c3 += bf_hi(r3.y);
    c4 += bf_lo(r3.z); c5 += bf_hi(r3.z); c6 += bf_lo(r3.w); c7 += bf_hi(r3.w);
  }
  for (; j < cnt; j++) {
    int u = csr[base + j];
    uint4 r = P1v[(size_t)u * 8 + dg];
    a0 += bf_lo(r.x); a1 += bf_hi(r.x); a2 += bf_lo(r.y); a3 += bf_hi(r.y);
    a4 += bf_lo(r.z); a5 += bf_hi(r.z); a6 += bf_lo(r.w); a7 += bf_hi(r.w);
  }
  a0 += c0; a1 += c1; a2 += c2; a3 += c3;
  a4 += c4; a5 += c5; a6 += c6; a7 += c7;
  float dv = dinv[v];
  float4 bb0 = ((const float4*)b1)[dg * 2];
  float4 bb1 = ((const float4*)b1)[dg * 2 + 1];
  bf16x8 hv;
  hv[0] = (bf16_t)fmaxf(dv * a0 + bb0.x, 0.f);
  hv[1] = (bf16_t)fmaxf(dv * a1 + bb0.y, 0.f);
  hv[2] = (bf16_t)fmaxf(dv * a2 + bb0.z, 0.f);
  hv[3] = (bf16_t)fmaxf(dv * a3 + bb0.w, 0.f);
  hv[4] = (bf16_t)fmaxf(dv * a4 + bb1.x, 0.f);
  hv[5] = (bf16_t)fmaxf(dv * a5 + bb1.y, 0.f);
  hv[6] = (bf16_t)fmaxf(dv * a6 + bb1.z, 0.f);
  hv[7] = (bf16_t)fmaxf(dv * a7 + bb1.w, 0.f);
  ((bf16x8*)h)[(size_t)v * 8 + dg] = hv;
}

// GEMM2 via MFMA: P2[n][32] (bf16) = dinv[n] * (h[n] @ W2)
__global__ __launch_bounds__(256) void k_gemm2(const bf16_t* __restrict__ h,
                                               const bf16_t* __restrict__ w2t,
                                               const float* __restrict__ dinv,
                                               bf16_t* __restrict__ P2, int n) {
  int t = threadIdx.x;
  int w = t >> 6, l = t & 63;
  int rowBase = blockIdx.x * 64 + w * 16;
  int fr = l & 15, fk = l >> 4;
  int ar = rowBase + fr; if (ar >= n) ar = n - 1;
  const bf16_t* hp = h + (size_t)ar * FH + fk * 8;
  const bf16_t* wb0 = w2t + (size_t)fr * FH + fk * 8;
  const bf16_t* wb1 = w2t + (size_t)(fr + 16) * FH + fk * 8;

  f32x4 acc0 = {0.f, 0.f, 0.f, 0.f};
  f32x4 acc1 = {0.f, 0.f, 0.f, 0.f};
  #pragma unroll
  for (int kt = 0; kt < FH; kt += 32) {
    bf16x8 af = *(const bf16x8*)(hp + kt);
    bf16x8 b0 = *(const bf16x8*)(wb0 + kt);
    bf16x8 b1 = *(const bf16x8*)(wb1 + kt);
    acc0 = __builtin_amdgcn_mfma_f32_16x16x32_bf16(af, b0, acc0, 0, 0, 0);
    acc1 = __builtin_amdgcn_mfma_f32_16x16x32_bf16(af, b1, acc1, 0, 0, 0);
  }
  #pragma unroll
  for (int rg = 0; rg < 4; rg++) {
    int grow = rowBase + fk * 4 + rg;
    if (grow < n) {
      float dv = dinv[grow];
      P2[(size_t)grow * FO + fr]      = (bf16_t)(dv * acc0[rg]);
      P2[(size_t)grow * FO + fr + 16] = (bf16_t)(dv * acc1[rg]);
    }
  }
}

// gather2 + bias + log_softmax: wave = 16 subgroups x 4 lanes x uint4; one node each.
__global__ __launch_bounds__(256) void k_g2final(const bf16_t* __restrict__ P2,
                                                 const int* __restrict__ csr,
                                                 const int* __restrict__ rowoff,
                                                 const float* __restrict__ dinv,
                                                 const float* __restrict__ b2,
                                                 float* __restrict__ out, int n) {
  int l = threadIdx.x & 63;
  int sg = l >> 2, dg = l & 3;
  int wv = (blockIdx.x * 256 + threadIdx.x) >> 6;
  int v = wv * 16 + sg;
  if (v >= n) return;
  const uint4* P2v = (const uint4*)P2;
  int base = rowoff[v];
  int cnt = rowoff[v + 1] - base;
  uint4 sv = P2v[(size_t)v * 4 + dg];  // self loop
  float a0 = bf_lo(sv.x), a1 = bf_hi(sv.x), a2 = bf_lo(sv.y), a3 = bf_hi(sv.y);
  float a4 = bf_lo(sv.z), a5 = bf_hi(sv.z), a6 = bf_lo(sv.w), a7 = bf_hi(sv.w);
  float c0 = 0.f, c1 = 0.f, c2 = 0.f, c3 = 0.f, c4 = 0.f, c5 = 0.f, c6 = 0.f, c7 = 0.f;
  int cnt4 = cnt & ~3;
  int j = 0;
  for (; j < cnt4; j += 4) {
    int u0 = csr[base + j];
    int u1 = csr[base + j + 1];
    int u2 = csr[base + j + 2];
    int u3 = csr[base + j + 3];
    uint4 r0 = P2v[(size_t)u0 * 4 + dg];
    uint4 r1 = P2v[(size_t)u1 * 4 + dg];
    uint4 r2 = P2v[(size_t)u2 * 4 + dg];
    uint4 r3 = P2v[(size_t)u3 * 4 + dg];
    a0 += bf_lo(r0.x); a1 += bf_hi(r0.x); a2 += bf_lo(r0.y); a3 += bf_hi(r0.y);
    a4 += bf_lo(r0.z); a5 += bf_hi(r0.z); a6 += bf_lo(r0.w); a7 += bf_hi(r0.w);
    c0 += bf_lo(r1.x); c1 += bf_hi(r1.x); c2 += bf_lo(r1.y); c3 += bf_hi(r1.y);
    c4 += bf_lo(r1.z); c5 += bf_hi(r1.z); c6 += bf_lo(r1.w); c7 += bf_hi(r1.w);
    a0 += bf_lo(r2.x); a1 += bf_hi(r2.x); a2 += bf_lo(r2.y); a3 += bf_hi(r2.y);
    a4 += bf_lo(r2.z); a5 += bf_hi(r2.z); a6 += bf_lo(r2.w); a7 += bf_hi(r2.w);
    c0 += bf_lo(r3.x); c1 += bf_hi(r3.x); c2 += bf_lo(r3.y); c3 += bf_hi(r3.y);
    c4 += bf_lo(r3.z); c5 += bf_hi(r3.z); c6 += bf_lo(r3.w); c7 += bf_hi(r3.w);
  }
  for (; j < cnt; j++) {
    int u = csr[base + j];
    uint4 r = P2v[(size_t)u * 4 + dg];
    a0 += bf_lo(r.x); a1 += bf_hi(r.x); a2 += bf_lo(r.y); a3 += bf_hi(r.y);
    a4 += bf_lo(r.z); a5 += bf_hi(r.z); a6 += bf_lo(r.w); a7 += bf_hi(r.w);
  }
  a0 += c0; a1 += c1; a2 += c2; a3 += c3;
  a4 += c4; a5 += c5; a6 += c6; a7 += c7;
  float dv = dinv[v];
  float4 bb0 = ((const float4*)b2)[dg * 2];
  float4 bb1 = ((const float4*)b2)[dg * 2 + 1];
  float val[8];
  val[0] = dv * a0 + bb0.x; val[1] = dv * a1 + bb0.y;
  val[2] = dv * a2 + bb0.z; val[3] = dv * a3 + bb0.w;
  val[4] = dv * a4 + bb1.x; val[5] = dv * a5 + bb1.y;
  val[6] = dv * a6 + bb1.z; val[7] = dv * a7 + bb1.w;
  float m = val[0];
  #pragma unroll
  for (int q = 1; q < 8; q++) m = fmaxf(m, val[q]);
  m = fmaxf(m, __shfl_xor(m, 1, 64));
  m = fmaxf(m, __shfl_xor(m, 2, 64));
  float se = 0.f;
  #pragma unroll
  for (int q = 0; q < 8; q++) se += expf(val[q] - m);
  se += __shfl_xor(se, 1, 64);
  se += __shfl_xor(se, 2, 64);
  float lse = m + logf(se);
  float4 o0, o1;
  o0.x = val[0] - lse; o0.y = val[1] - lse; o0.z = val[2] - lse; o0.w = val[3] - lse;
  o1.x = val[4] - lse; o1.y = val[5] - lse; o1.z = val[6] - lse; o1.w = val[7] - lse;
  float* orow = out + (size_t)v * FO + dg * 8;
  *(float4*)orow = o0;
  *(float4*)(orow + 4) = o1;
}

extern "C" void kernel_launch(void* const* d_in, const int* in_sizes, int n_in,
                              void* d_out, int out_size, void* d_ws, size_t ws_size,
                              hipStream_t stream) {
  const float* x  = (const float*)d_in[0];
  const int*   ei = (const int*)d_in[1];
  const float* W1 = (const float*)d_in[2];
  const float* b1 = (const float*)d_in[3];
  const float* W2 = (const float*)d_in[4];
  const float* b2 = (const float*)d_in[5];
  const int N = in_sizes[0] / FIN;
  const int E = in_sizes[1] / 2;
  float* out = (float*)d_out;

  size_t NP = ((size_t)N + 63) & ~(size_t)63;
  size_t EP = ((size_t)E + 63) & ~(size_t)63;
  int NB = (N + BNODES - 1) >> BSH;

  int*      histmat = (int*)d_ws;                        // NBMAX*NCHUNK
  int*      rowscan = histmat + (size_t)NBMAX * NCHUNK;  // NBMAX*NCHUNK
  int*      rowsum  = rowscan + (size_t)NBMAX * NCHUNK;  // NBMAX
  int*      rowoff  = rowsum + NBMAX;                    // NP+64 (incl sentinel)
  float*    dinv    = (float*)(rowoff + NP + 64);        // NP
  int*      csr     = (int*)(dinv + NP);                 // EP
  unsigned* part    = (unsigned*)(csr + EP);             // EP
  bf16_t*   w1t     = (bf16_t*)(part + EP);              // 64*512
  bf16_t*   w2t     = w1t + (size_t)FH * FIN;            // 32*64
  bf16_t*   P1      = w2t + (size_t)FO * FH;             // NP*64
  bf16_t*   h       = P1 + NP * FH;                      // NP*64
  bf16_t*   P2      = h + NP * FH;                       // NP*32

  k_init<<<(FIN * FH + 255) / 256, 256, 0, stream>>>(W1, w1t, W2, w2t);
  k_histA<<<NCHUNK, 256, 0, stream>>>(ei + E, histmat, E, NB);
  k_scanB<<<NB, 256, 0, stream>>>(histmat, rowscan, rowsum, NB);
  k_scatC<<<NCHUNK, 256, 0, stream>>>(ei, rowscan, rowsum, part, E, NB);
  k_csrb<<<NB, 256, 0, stream>>>(part, rowsum, csr, rowoff, dinv, N, NB);
  k_gemm1<<<(N + 63) / 64, 256, 0, stream>>>(x, w1t, dinv, P1, N);
  {
    int waves = (N + 7) / 8;
    k_gather1<<<(waves + 3) / 4, 256, 0, stream>>>(P1, csr, rowoff, dinv, b1, h, N);
  }
  k_gemm2<<<(N + 63) / 64, 256, 0, stream>>>(h, w2t, dinv, P2, N);
  {
    int waves = (N + 15) / 16;
    k_g2final<<<(waves + 3) / 4, 256, 0, stream>>>(P2, csr, rowoff, dinv, b2, out, N);
  }
}

// Round 13
// 194.553 us; speedup vs baseline: 6.2786x; 1.0439x over previous
//
#include <hip/hip_runtime.h>
#include <math.h>

#define FIN 512
#define FH  64
#define FO  32

#define BSH    9          // 512 nodes per dst-bucket
#define BNODES 512
#define NCHUNK 256        // radix chunk-blocks
#define BCAP   10240      // LDS csr capacity per bucket (mean 8192, sigma ~90)
#define NBMAX  512

typedef __bf16 bf16_t;
typedef bf16_t bf16x8 __attribute__((ext_vector_type(8)));
typedef float  f32x4  __attribute__((ext_vector_type(4)));
typedef float  f32x2  __attribute__((ext_vector_type(2)));

__device__ __forceinline__ float bf_lo(unsigned u) {
  return __builtin_bit_cast(float, u << 16);
}
__device__ __forceinline__ float bf_hi(unsigned u) {
  return __builtin_bit_cast(float, u & 0xffff0000u);
}
__device__ __forceinline__ unsigned char f32_to_fp8(float v) {
  int p = __builtin_amdgcn_cvt_pk_fp8_f32(v, v, 0, false);
  return (unsigned char)(p & 0xff);
}

// radix pass A + weight-convert riders
__global__ __launch_bounds__(256) void k_histA(const int* __restrict__ dst,
                                               int* __restrict__ histmat,
                                               int E, int NB,
                                               const float* __restrict__ W1,
                                               bf16_t* __restrict__ w1t,
                                               const float* __restrict__ W2,
                                               bf16_t* __restrict__ w2t) {
  if (blockIdx.x >= NCHUNK) {
    int i = (blockIdx.x - NCHUNK) * 256 + threadIdx.x;
    if (i < FIN * FH) {
      int c = i >> 9, k = i & 511;
      w1t[i] = (bf16_t)W1[(size_t)k * FH + c];
    }
    if (i < FH * FO) {
      int c = i >> 6, k = i & 63;
      w2t[i] = (bf16_t)W2[(size_t)k * FO + c];
    }
    return;
  }
  __shared__ int lh[NBMAX];
  int t = threadIdx.x;
  int g = blockIdx.x;
  for (int i = t; i < NB; i += 256) lh[i] = 0;
  __syncthreads();
  int C = (E + NCHUNK - 1) / NCHUNK;
  int e0 = g * C, e1 = min(E, e0 + C);
  for (int e = e0 + t; e < e1; e += 256) {
    atomicAdd(&lh[dst[e] >> BSH], 1);
  }
  __syncthreads();
  for (int b = t; b < NB; b += 256) histmat[(size_t)b * NCHUNK + g] = lh[b];
}

// radix pass B: per-bucket exclusive scan over chunks -> rowscan, total -> rowsum
__global__ __launch_bounds__(256) void k_scanB(const int* __restrict__ histmat,
                                               int* __restrict__ rowscan,
                                               int* __restrict__ rowsum, int NB) {
  __shared__ int s[NCHUNK];
  int b = blockIdx.x;
  int t = threadIdx.x;
  int v = histmat[(size_t)b * NCHUNK + t];
  s[t] = v;
  __syncthreads();
  #pragma unroll
  for (int off = 1; off < NCHUNK; off <<= 1) {
    int tmp = (t >= off) ? s[t - off] : 0;
    __syncthreads();
    s[t] += tmp;
    __syncthreads();
  }
  rowscan[(size_t)b * NCHUNK + t] = s[t] - v;
  if (t == 255) rowsum[b] = s[255];
}

// radix pass C: scatter packed (dlocal<<23 | src) into bucket-grouped part[]
__global__ __launch_bounds__(256) void k_scatC(const int* __restrict__ ei,
                                               const int* __restrict__ rowscan,
                                               const int* __restrict__ rowsum,
                                               unsigned* __restrict__ part,
                                               int E, int NB) {
  __shared__ int lcur[NBMAX];
  __shared__ int sc[256];
  int t = threadIdx.x;
  int g = blockIdx.x;
  int carry = 0;
  for (int bb = 0; bb < NB; bb += 256) {
    int idx = bb + t;
    int v = (idx < NB) ? rowsum[idx] : 0;
    sc[t] = v;
    __syncthreads();
    #pragma unroll
    for (int off = 1; off < 256; off <<= 1) {
      int tmp = (t >= off) ? sc[t - off] : 0;
      __syncthreads();
      sc[t] += tmp;
      __syncthreads();
    }
    if (idx < NB) lcur[idx] = sc[t] - v + carry + rowscan[(size_t)idx * NCHUNK + g];
    carry += sc[255];
    __syncthreads();
  }
  __syncthreads();
  int C = (E + NCHUNK - 1) / NCHUNK;
  int e0 = g * C, e1 = min(E, e0 + C);
  for (int e = e0 + t; e < e1; e += 256) {
    int s = ei[e];
    int d = ei[E + e];
    int b = d >> BSH;
    int pos = atomicAdd(&lcur[b], 1);
    part[pos] = (unsigned)s | ((unsigned)(d & (BNODES - 1)) << 23);
  }
}

// per-bucket CSR build; writes csr (node-sorted), rowoff, dinv
__global__ __launch_bounds__(256) void k_csrb(const unsigned* __restrict__ part,
                                              const int* __restrict__ rowsum,
                                              int* __restrict__ csr,
                                              int* __restrict__ rowoff,
                                              float* __restrict__ dinv,
                                              int n, int NB) {
  __shared__ int sc[256];
  __shared__ int lhist[BNODES];
  __shared__ int lro[BNODES];
  __shared__ int lcur[BNODES];
  __shared__ int lcsr[BCAP];
  int b = blockIdx.x;
  int t = threadIdx.x;
  int base = b << BSH;

  int partial = 0;
  for (int i = t; i < b; i += 256) partial += rowsum[i];
  sc[t] = partial;
  __syncthreads();
  #pragma unroll
  for (int off = 128; off > 0; off >>= 1) {
    if (t < off) sc[t] += sc[t + off];
    __syncthreads();
  }
  int bo = sc[0];
  int cnt = rowsum[b];
  __syncthreads();

  for (int i = t; i < BNODES; i += 256) lhist[i] = 0;
  __syncthreads();
  const unsigned* pp = part + bo;
  for (int j = t; j < cnt; j += 256) atomicAdd(&lhist[pp[j] >> 23], 1);
  __syncthreads();

  int v0 = lhist[t];
  sc[t] = v0;
  __syncthreads();
  #pragma unroll
  for (int off = 1; off < 256; off <<= 1) {
    int tmp = (t >= off) ? sc[t - off] : 0;
    __syncthreads();
    sc[t] += tmp;
    __syncthreads();
  }
  lro[t] = sc[t] - v0;
  int tot0 = sc[255];
  __syncthreads();
  int v1 = lhist[256 + t];
  sc[t] = v1;
  __syncthreads();
  #pragma unroll
  for (int off = 1; off < 256; off <<= 1) {
    int tmp = (t >= off) ? sc[t - off] : 0;
    __syncthreads();
    sc[t] += tmp;
    __syncthreads();
  }
  lro[256 + t] = sc[t] - v1 + tot0;
  __syncthreads();

  for (int i = t; i < BNODES; i += 256) {
    int v = base + i;
    if (v < n) {
      rowoff[v] = bo + lro[i];
      dinv[v] = rsqrtf((float)(lhist[i] + 1));
    }
    lcur[i] = 0;
  }
  if (t == 0 && base + BNODES >= n) rowoff[n] = bo + cnt;
  __syncthreads();

  if (cnt <= BCAP) {
    for (int j = t; j < cnt; j += 256) {
      unsigned pk = pp[j];
      int dl = (int)(pk >> 23);
      int pos = atomicAdd(&lcur[dl], 1);
      lcsr[lro[dl] + pos] = (int)(pk & 0x7FFFFFu);
    }
    __syncthreads();
    for (int j = t; j < cnt; j += 256) csr[bo + j] = lcsr[j];
  } else {
    for (int j = t; j < cnt; j += 256) {
      unsigned pk = pp[j];
      int dl = (int)(pk >> 23);
      int pos = atomicAdd(&lcur[dl], 1);
      csr[bo + lro[dl] + pos] = (int)(pk & 0x7FFFFFu);
    }
  }
}

// GEMM1 via MFMA: P1[n][64] (fp8 e4m3) = dinv[n] * (x[n] @ W1)
__global__ __launch_bounds__(256) void k_gemm1(const float* __restrict__ x,
                                               const bf16_t* __restrict__ w1t,
                                               const float* __restrict__ dinv,
                                               unsigned char* __restrict__ P1, int n) {
  int t = threadIdx.x;
  int w = t >> 6, l = t & 63;
  int rowBase = blockIdx.x * 64 + w * 16;
  int fr = l & 15, fk = l >> 4;
  int ar = rowBase + fr; if (ar >= n) ar = n - 1;
  const float* xp = x + (size_t)ar * FIN + fk * 8;
  const bf16_t* wb = w1t + (size_t)fr * FIN + fk * 8;

  f32x4 acc0 = {0.f, 0.f, 0.f, 0.f};
  f32x4 acc1 = {0.f, 0.f, 0.f, 0.f};
  f32x4 acc2 = {0.f, 0.f, 0.f, 0.f};
  f32x4 acc3 = {0.f, 0.f, 0.f, 0.f};

  #pragma unroll 4
  for (int kt = 0; kt < FIN; kt += 32) {
    float4 a0 = *(const float4*)(xp + kt);
    float4 a1 = *(const float4*)(xp + kt + 4);
    bf16x8 av;
    av[0] = (bf16_t)a0.x; av[1] = (bf16_t)a0.y; av[2] = (bf16_t)a0.z; av[3] = (bf16_t)a0.w;
    av[4] = (bf16_t)a1.x; av[5] = (bf16_t)a1.y; av[6] = (bf16_t)a1.z; av[7] = (bf16_t)a1.w;
    bf16x8 b0 = *(const bf16x8*)(wb + kt);
    bf16x8 b1 = *(const bf16x8*)(wb + (size_t)16 * FIN + kt);
    bf16x8 b2 = *(const bf16x8*)(wb + (size_t)32 * FIN + kt);
    bf16x8 b3 = *(const bf16x8*)(wb + (size_t)48 * FIN + kt);
    acc0 = __builtin_amdgcn_mfma_f32_16x16x32_bf16(av, b0, acc0, 0, 0, 0);
    acc1 = __builtin_amdgcn_mfma_f32_16x16x32_bf16(av, b1, acc1, 0, 0, 0);
    acc2 = __builtin_amdgcn_mfma_f32_16x16x32_bf16(av, b2, acc2, 0, 0, 0);
    acc3 = __builtin_amdgcn_mfma_f32_16x16x32_bf16(av, b3, acc3, 0, 0, 0);
  }

  #pragma unroll
  for (int rg = 0; rg < 4; rg++) {
    int grow = rowBase + fk * 4 + rg;
    if (grow < n) {
      float dv = dinv[grow];
      unsigned char* prow = P1 + (size_t)grow * FH + fr;
      prow[0]  = f32_to_fp8(dv * acc0[rg]);
      prow[16] = f32_to_fp8(dv * acc1[rg]);
      prow[32] = f32_to_fp8(dv * acc2[rg]);
      prow[48] = f32_to_fp8(dv * acc3[rg]);
    }
  }
}

// gather1 (fp8 rows, 64B): wave = 16 subgroups x 4 lanes x uint4; one node each.
// 4-unrolled -> 64 rows in flight per wave. h = relu(dinv*sum + b1) -> bf16.
__global__ __launch_bounds__(256) void k_gather1(const unsigned char* __restrict__ P1,
                                                 const int* __restrict__ csr,
                                                 const int* __restrict__ rowoff,
                                                 const float* __restrict__ dinv,
                                                 const float* __restrict__ b1,
                                                 bf16_t* __restrict__ h, int n) {
  int l = threadIdx.x & 63;
  int sg = l >> 2, dg = l & 3;    // lane covers dims dg*16 .. dg*16+15
  int wv = (blockIdx.x * 256 + threadIdx.x) >> 6;
  int v = wv * 16 + sg;
  if (v >= n) return;
  const uint4* P1v = (const uint4*)P1;
  int base = rowoff[v];
  int cnt = rowoff[v + 1] - base;

  float a[16], c[16];
  {
    uint4 r = P1v[(size_t)v * 4 + dg];  // self loop
    f32x2 d0 = __builtin_amdgcn_cvt_pk_f32_fp8((int)r.x, false);
    f32x2 d1 = __builtin_amdgcn_cvt_pk_f32_fp8((int)r.x, true);
    f32x2 d2 = __builtin_amdgcn_cvt_pk_f32_fp8((int)r.y, false);
    f32x2 d3 = __builtin_amdgcn_cvt_pk_f32_fp8((int)r.y, true);
    f32x2 d4 = __builtin_amdgcn_cvt_pk_f32_fp8((int)r.z, false);
    f32x2 d5 = __builtin_amdgcn_cvt_pk_f32_fp8((int)r.z, true);
    f32x2 d6 = __builtin_amdgcn_cvt_pk_f32_fp8((int)r.w, false);
    f32x2 d7 = __builtin_amdgcn_cvt_pk_f32_fp8((int)r.w, true);
    a[0] = d0[0]; a[1] = d0[1]; a[2] = d1[0]; a[3] = d1[1];
    a[4] = d2[0]; a[5] = d2[1]; a[6] = d3[0]; a[7] = d3[1];
    a[8] = d4[0]; a[9] = d4[1]; a[10] = d5[0]; a[11] = d5[1];
    a[12] = d6[0]; a[13] = d6[1]; a[14] = d7[0]; a[15] = d7[1];
    #pragma unroll
    for (int k = 0; k < 16; k++) c[k] = 0.f;
  }

  #define ACC16(dst, r) { \
    f32x2 d0 = __builtin_amdgcn_cvt_pk_f32_fp8((int)(r).x, false); \
    f32x2 d1 = __builtin_amdgcn_cvt_pk_f32_fp8((int)(r).x, true);  \
    f32x2 d2 = __builtin_amdgcn_cvt_pk_f32_fp8((int)(r).y, false); \
    f32x2 d3 = __builtin_amdgcn_cvt_pk_f32_fp8((int)(r).y, true);  \
    f32x2 d4 = __builtin_amdgcn_cvt_pk_f32_fp8((int)(r).z, false); \
    f32x2 d5 = __builtin_amdgcn_cvt_pk_f32_fp8((int)(r).z, true);  \
    f32x2 d6 = __builtin_amdgcn_cvt_pk_f32_fp8((int)(r).w, false); \
    f32x2 d7 = __builtin_amdgcn_cvt_pk_f32_fp8((int)(r).w, true);  \
    dst[0] += d0[0]; dst[1] += d0[1]; dst[2] += d1[0]; dst[3] += d1[1]; \
    dst[4] += d2[0]; dst[5] += d2[1]; dst[6] += d3[0]; dst[7] += d3[1]; \
    dst[8] += d4[0]; dst[9] += d4[1]; dst[10] += d5[0]; dst[11] += d5[1]; \
    dst[12] += d6[0]; dst[13] += d6[1]; dst[14] += d7[0]; dst[15] += d7[1]; }

  int cnt4 = cnt & ~3;
  int j = 0;
  for (; j < cnt4; j += 4) {
    int u0 = csr[base + j];
    int u1 = csr[base + j + 1];
    int u2 = csr[base + j + 2];
    int u3 = csr[base + j + 3];
    uint4 r0 = P1v[(size_t)u0 * 4 + dg];
    uint4 r1 = P1v[(size_t)u1 * 4 + dg];
    uint4 r2 = P1v[(size_t)u2 * 4 + dg];
    uint4 r3 = P1v[(size_t)u3 * 4 + dg];
    ACC16(a, r0);
    ACC16(c, r1);
    ACC16(a, r2);
    ACC16(c, r3);
  }
  for (; j < cnt; j++) {
    int u = csr[base + j];
    uint4 r = P1v[(size_t)u * 4 + dg];
    ACC16(a, r);
  }
  #undef ACC16

  float dv = dinv[v];
  const float4* b1v = (const float4*)b1;
  bf16x8 hv0, hv1;
  #pragma unroll
  for (int q = 0; q < 4; q++) {
    float4 bb = b1v[dg * 4 + q];
    float s0 = fmaxf(dv * (a[q*4+0] + c[q*4+0]) + bb.x, 0.f);
    float s1 = fmaxf(dv * (a[q*4+1] + c[q*4+1]) + bb.y, 0.f);
    float s2 = fmaxf(dv * (a[q*4+2] + c[q*4+2]) + bb.z, 0.f);
    float s3 = fmaxf(dv * (a[q*4+3] + c[q*4+3]) + bb.w, 0.f);
    if (q < 2) {
      hv0[q*4+0] = (bf16_t)s0; hv0[q*4+1] = (bf16_t)s1;
      hv0[q*4+2] = (bf16_t)s2; hv0[q*4+3] = (bf16_t)s3;
    } else {
      hv1[(q-2)*4+0] = (bf16_t)s0; hv1[(q-2)*4+1] = (bf16_t)s1;
      hv1[(q-2)*4+2] = (bf16_t)s2; hv1[(q-2)*4+3] = (bf16_t)s3;
    }
  }
  ((bf16x8*)h)[(size_t)v * 8 + dg * 2]     = hv0;
  ((bf16x8*)h)[(size_t)v * 8 + dg * 2 + 1] = hv1;
}

// GEMM2 via MFMA: P2[n][32] (bf16) = dinv[n] * (h[n] @ W2)
__global__ __launch_bounds__(256) void k_gemm2(const bf16_t* __restrict__ h,
                                               const bf16_t* __restrict__ w2t,
                                               const float* __restrict__ dinv,
                                               bf16_t* __restrict__ P2, int n) {
  int t = threadIdx.x;
  int w = t >> 6, l = t & 63;
  int rowBase = blockIdx.x * 64 + w * 16;
  int fr = l & 15, fk = l >> 4;
  int ar = rowBase + fr; if (ar >= n) ar = n - 1;
  const bf16_t* hp = h + (size_t)ar * FH + fk * 8;
  const bf16_t* wb0 = w2t + (size_t)fr * FH + fk * 8;
  const bf16_t* wb1 = w2t + (size_t)(fr + 16) * FH + fk * 8;

  f32x4 acc0 = {0.f, 0.f, 0.f, 0.f};
  f32x4 acc1 = {0.f, 0.f, 0.f, 0.f};
  #pragma unroll
  for (int kt = 0; kt < FH; kt += 32) {
    bf16x8 af = *(const bf16x8*)(hp + kt);
    bf16x8 b0 = *(const bf16x8*)(wb0 + kt);
    bf16x8 b1 = *(const bf16x8*)(wb1 + kt);
    acc0 = __builtin_amdgcn_mfma_f32_16x16x32_bf16(af, b0, acc0, 0, 0, 0);
    acc1 = __builtin_amdgcn_mfma_f32_16x16x32_bf16(af, b1, acc1, 0, 0, 0);
  }
  #pragma unroll
  for (int rg = 0; rg < 4; rg++) {
    int grow = rowBase + fk * 4 + rg;
    if (grow < n) {
      float dv = dinv[grow];
      P2[(size_t)grow * FO + fr]      = (bf16_t)(dv * acc0[rg]);
      P2[(size_t)grow * FO + fr + 16] = (bf16_t)(dv * acc1[rg]);
    }
  }
}

// gather2 + bias + log_softmax: wave = 16 subgroups x 4 lanes x uint4; one node each.
__global__ __launch_bounds__(256) void k_g2final(const bf16_t* __restrict__ P2,
                                                 const int* __restrict__ csr,
                                                 const int* __restrict__ rowoff,
                                                 const float* __restrict__ dinv,
                                                 const float* __restrict__ b2,
                                                 float* __restrict__ out, int n) {
  int l = threadIdx.x & 63;
  int sg = l >> 2, dg = l & 3;
  int wv = (blockIdx.x * 256 + threadIdx.x) >> 6;
  int v = wv * 16 + sg;
  if (v >= n) return;
  const uint4* P2v = (const uint4*)P2;
  int base = rowoff[v];
  int cnt = rowoff[v + 1] - base;
  uint4 sv = P2v[(size_t)v * 4 + dg];  // self loop
  float a0 = bf_lo(sv.x), a1 = bf_hi(sv.x), a2 = bf_lo(sv.y), a3 = bf_hi(sv.y);
  float a4 = bf_lo(sv.z), a5 = bf_hi(sv.z), a6 = bf_lo(sv.w), a7 = bf_hi(sv.w);
  float c0 = 0.f, c1 = 0.f, c2 = 0.f, c3 = 0.f, c4 = 0.f, c5 = 0.f, c6 = 0.f, c7 = 0.f;
  int cnt4 = cnt & ~3;
  int j = 0;
  for (; j < cnt4; j += 4) {
    int u0 = csr[base + j];
    int u1 = csr[base + j + 1];
    int u2 = csr[base + j + 2];
    int u3 = csr[base + j + 3];
    uint4 r0 = P2v[(size_t)u0 * 4 + dg];
    uint4 r1 = P2v[(size_t)u1 * 4 + dg];
    uint4 r2 = P2v[(size_t)u2 * 4 + dg];
    uint4 r3 = P2v[(size_t)u3 * 4 + dg];
    a0 += bf_lo(r0.x); a1 += bf_hi(r0.x); a2 += bf_lo(r0.y); a3 += bf_hi(r0.y);
    a4 += bf_lo(r0.z); a5 += bf_hi(r0.z); a6 += bf_lo(r0.w); a7 += bf_hi(r0.w);
    c0 += bf_lo(r1.x); c1 += bf_hi(r1.x); c2 += bf_lo(r1.y); c3 += bf_hi(r1.y);
    c4 += bf_lo(r1.z); c5 += bf_hi(r1.z); c6 += bf_lo(r1.w); c7 += bf_hi(r1.w);
    a0 += bf_lo(r2.x); a1 += bf_hi(r2.x); a2 += bf_lo(r2.y); a3 += bf_hi(r2.y);
    a4 += bf_lo(r2.z); a5 += bf_hi(r2.z); a6 += bf_lo(r2.w); a7 += bf_hi(r2.w);
    c0 += bf_lo(r3.x); c1 += bf_hi(r3.x); c2 += bf_lo(r3.y); c3 += bf_hi(r3.y);
    c4 += bf_lo(r3.z); c5 += bf_hi(r3.z); c6 += bf_lo(r3.w); c7 += bf_hi(r3.w);
  }
  for (; j < cnt; j++) {
    int u = csr[base + j];
    uint4 r = P2v[(size_t)u * 4 + dg];
    a0 += bf_lo(r.x); a1 += bf_hi(r.x); a2 += bf_lo(r.y); a3 += bf_hi(r.y);
    a4 += bf_lo(r.z); a5 += bf_hi(r.z); a6 += bf_lo(r.w); a7 += bf_hi(r.w);
  }
  a0 += c0; a1 += c1; a2 += c2; a3 += c3;
  a4 += c4; a5 += c5; a6 += c6; a7 += c7;
  float dv = dinv[v];
  float4 bb0 = ((const float4*)b2)[dg * 2];
  float4 bb1 = ((const float4*)b2)[dg * 2 + 1];
  float val[8];
  val[0] = dv * a0 + bb0.x; val[1] = dv * a1 + bb0.y;
  val[2] = dv * a2 + bb0.z; val[3] = dv * a3 + bb0.w;
  val[4] = dv * a4 + bb1.x; val[5] = dv * a5 + bb1.y;
  val[6] = dv * a6 + bb1.z; val[7] = dv * a7 + bb1.w;
  float m = val[0];
  #pragma unroll
  for (int q = 1; q < 8; q++) m = fmaxf(m, val[q]);
  m = fmaxf(m, __shfl_xor(m, 1, 64));
  m = fmaxf(m, __shfl_xor(m, 2, 64));
  float se = 0.f;
  #pragma unroll
  for (int q = 0; q < 8; q++) se += expf(val[q] - m);
  se += __shfl_xor(se, 1, 64);
  se += __shfl_xor(se, 2, 64);
  float lse = m + logf(se);
  float4 o0, o1;
  o0.x = val[0] - lse; o0.y = val[1] - lse; o0.z = val[2] - lse; o0.w = val[3] - lse;
  o1.x = val[4] - lse; o1.y = val[5] - lse; o1.z = val[6] - lse; o1.w = val[7] - lse;
  float* orow = out + (size_t)v * FO + dg * 8;
  *(float4*)orow = o0;
  *(float4*)(orow + 4) = o1;
}

extern "C" void kernel_launch(void* const* d_in, const int* in_sizes, int n_in,
                              void* d_out, int out_size, void* d_ws, size_t ws_size,
                              hipStream_t stream) {
  const float* x  = (const float*)d_in[0];
  const int*   ei = (const int*)d_in[1];
  const float* W1 = (const float*)d_in[2];
  const float* b1 = (const float*)d_in[3];
  const float* W2 = (const float*)d_in[4];
  const float* b2 = (const float*)d_in[5];
  const int N = in_sizes[0] / FIN;
  const int E = in_sizes[1] / 2;
  float* out = (float*)d_out;

  size_t NP = ((size_t)N + 63) & ~(size_t)63;
  size_t EP = ((size_t)E + 63) & ~(size_t)63;
  int NB = (N + BNODES - 1) >> BSH;

  int*           histmat = (int*)d_ws;                        // NBMAX*NCHUNK
  int*           rowscan = histmat + (size_t)NBMAX * NCHUNK;  // NBMAX*NCHUNK
  int*           rowsum  = rowscan + (size_t)NBMAX * NCHUNK;  // NBMAX
  int*           rowoff  = rowsum + NBMAX;                    // NP+64 (incl sentinel)
  float*         dinv    = (float*)(rowoff + NP + 64);        // NP
  int*           csr     = (int*)(dinv + NP);                 // EP
  unsigned*      part    = (unsigned*)(csr + EP);             // EP
  bf16_t*        w1t     = (bf16_t*)(part + EP);              // 64*512
  bf16_t*        w2t     = w1t + (size_t)FH * FIN;            // 32*64
  unsigned char* P1      = (unsigned char*)(w2t + (size_t)FO * FH);  // NP*64 bytes
  bf16_t*        h       = (bf16_t*)(P1 + NP * FH);           // NP*64
  bf16_t*        P2      = h + NP * FH;                       // NP*32

  int wconvB = (FIN * FH + 255) / 256;  // 128 rider blocks
  k_histA<<<NCHUNK + wconvB, 256, 0, stream>>>(ei + E, histmat, E, NB, W1, w1t, W2, w2t);
  k_scanB<<<NB, 256, 0, stream>>>(histmat, rowscan, rowsum, NB);
  k_scatC<<<NCHUNK, 256, 0, stream>>>(ei, rowscan, rowsum, part, E, NB);
  k_csrb<<<NB, 256, 0, stream>>>(part, rowsum, csr, rowoff, dinv, N, NB);
  k_gemm1<<<(N + 63) / 64, 256, 0, stream>>>(x, w1t, dinv, P1, N);
  {
    int waves = (N + 15) / 16;
    k_gather1<<<(waves + 3) / 4, 256, 0, stream>>>(P1, csr, rowoff, dinv, b1, h, N);
  }
  k_gemm2<<<(N + 63) / 64, 256, 0, stream>>>(h, w2t, dinv, P2, N);
  {
    int waves = (N + 15) / 16;
    k_g2final<<<(waves + 3) / 4, 256, 0, stream>>>(P2, csr, rowoff, dinv, b2, out, N);
  }
}

// Round 14
// 187.009 us; speedup vs baseline: 6.5319x; 1.0403x over previous
//
#include <hip/hip_runtime.h>
#include <math.h>

#define FIN 512
#define FH  64
#define FO  32

#define BSH    9          // 512 nodes per dst-bucket
#define BNODES 512
#define NCHUNK 256        // radix chunk-blocks
#define BCAP   10240      // LDS csr capacity per bucket (mean 8192, sigma ~90)
#define NBMAX  512

typedef __bf16 bf16_t;
typedef bf16_t bf16x8 __attribute__((ext_vector_type(8)));
typedef float  f32x4  __attribute__((ext_vector_type(4)));
typedef float  f32x2  __attribute__((ext_vector_type(2)));

__device__ __forceinline__ float bf_lo(unsigned u) {
  return __builtin_bit_cast(float, u << 16);
}
__device__ __forceinline__ float bf_hi(unsigned u) {
  return __builtin_bit_cast(float, u & 0xffff0000u);
}
__device__ __forceinline__ unsigned char f32_to_fp8(float v) {
  int p = __builtin_amdgcn_cvt_pk_fp8_f32(v, v, 0, false);
  return (unsigned char)(p & 0xff);
}

// decode 16 fp8 (one uint4) and accumulate into dst[16]
#define ACC16(dst, r) { \
  f32x2 d0 = __builtin_amdgcn_cvt_pk_f32_fp8((int)(r).x, false); \
  f32x2 d1 = __builtin_amdgcn_cvt_pk_f32_fp8((int)(r).x, true);  \
  f32x2 d2 = __builtin_amdgcn_cvt_pk_f32_fp8((int)(r).y, false); \
  f32x2 d3 = __builtin_amdgcn_cvt_pk_f32_fp8((int)(r).y, true);  \
  f32x2 d4 = __builtin_amdgcn_cvt_pk_f32_fp8((int)(r).z, false); \
  f32x2 d5 = __builtin_amdgcn_cvt_pk_f32_fp8((int)(r).z, true);  \
  f32x2 d6 = __builtin_amdgcn_cvt_pk_f32_fp8((int)(r).w, false); \
  f32x2 d7 = __builtin_amdgcn_cvt_pk_f32_fp8((int)(r).w, true);  \
  dst[0] += d0[0]; dst[1] += d0[1]; dst[2] += d1[0]; dst[3] += d1[1]; \
  dst[4] += d2[0]; dst[5] += d2[1]; dst[6] += d3[0]; dst[7] += d3[1]; \
  dst[8] += d4[0]; dst[9] += d4[1]; dst[10] += d5[0]; dst[11] += d5[1]; \
  dst[12] += d6[0]; dst[13] += d6[1]; dst[14] += d7[0]; dst[15] += d7[1]; }

#define SET16(dst, r) { \
  f32x2 d0 = __builtin_amdgcn_cvt_pk_f32_fp8((int)(r).x, false); \
  f32x2 d1 = __builtin_amdgcn_cvt_pk_f32_fp8((int)(r).x, true);  \
  f32x2 d2 = __builtin_amdgcn_cvt_pk_f32_fp8((int)(r).y, false); \
  f32x2 d3 = __builtin_amdgcn_cvt_pk_f32_fp8((int)(r).y, true);  \
  f32x2 d4 = __builtin_amdgcn_cvt_pk_f32_fp8((int)(r).z, false); \
  f32x2 d5 = __builtin_amdgcn_cvt_pk_f32_fp8((int)(r).z, true);  \
  f32x2 d6 = __builtin_amdgcn_cvt_pk_f32_fp8((int)(r).w, false); \
  f32x2 d7 = __builtin_amdgcn_cvt_pk_f32_fp8((int)(r).w, true);  \
  dst[0] = d0[0]; dst[1] = d0[1]; dst[2] = d1[0]; dst[3] = d1[1]; \
  dst[4] = d2[0]; dst[5] = d2[1]; dst[6] = d3[0]; dst[7] = d3[1]; \
  dst[8] = d4[0]; dst[9] = d4[1]; dst[10] = d5[0]; dst[11] = d5[1]; \
  dst[12] = d6[0]; dst[13] = d6[1]; dst[14] = d7[0]; dst[15] = d7[1]; }

// radix pass A + weight-convert riders
__global__ __launch_bounds__(256) void k_histA(const int* __restrict__ dst,
                                               int* __restrict__ histmat,
                                               int E, int NB,
                                               const float* __restrict__ W1,
                                               bf16_t* __restrict__ w1t,
                                               const float* __restrict__ W2,
                                               bf16_t* __restrict__ w2t) {
  if (blockIdx.x >= NCHUNK) {
    int i = (blockIdx.x - NCHUNK) * 256 + threadIdx.x;
    if (i < FIN * FH) {
      int c = i >> 9, k = i & 511;
      w1t[i] = (bf16_t)W1[(size_t)k * FH + c];
    }
    if (i < FH * FO) {
      int c = i >> 6, k = i & 63;
      w2t[i] = (bf16_t)W2[(size_t)k * FO + c];
    }
    return;
  }
  __shared__ int lh[NBMAX];
  int t = threadIdx.x;
  int g = blockIdx.x;
  for (int i = t; i < NB; i += 256) lh[i] = 0;
  __syncthreads();
  int C = (E + NCHUNK - 1) / NCHUNK;
  int e0 = g * C, e1 = min(E, e0 + C);
  for (int e = e0 + t; e < e1; e += 256) {
    atomicAdd(&lh[dst[e] >> BSH], 1);
  }
  __syncthreads();
  for (int b = t; b < NB; b += 256) histmat[(size_t)b * NCHUNK + g] = lh[b];
}

// radix pass B: per-bucket exclusive scan over chunks -> rowscan, total -> rowsum
__global__ __launch_bounds__(256) void k_scanB(const int* __restrict__ histmat,
                                               int* __restrict__ rowscan,
                                               int* __restrict__ rowsum, int NB) {
  __shared__ int s[NCHUNK];
  int b = blockIdx.x;
  int t = threadIdx.x;
  int v = histmat[(size_t)b * NCHUNK + t];
  s[t] = v;
  __syncthreads();
  #pragma unroll
  for (int off = 1; off < NCHUNK; off <<= 1) {
    int tmp = (t >= off) ? s[t - off] : 0;
    __syncthreads();
    s[t] += tmp;
    __syncthreads();
  }
  rowscan[(size_t)b * NCHUNK + t] = s[t] - v;
  if (t == 255) rowsum[b] = s[255];
}

// radix pass C: scatter packed (dlocal<<23 | src) into bucket-grouped part[]
__global__ __launch_bounds__(256) void k_scatC(const int* __restrict__ ei,
                                               const int* __restrict__ rowscan,
                                               const int* __restrict__ rowsum,
                                               unsigned* __restrict__ part,
                                               int E, int NB) {
  __shared__ int lcur[NBMAX];
  __shared__ int sc[256];
  int t = threadIdx.x;
  int g = blockIdx.x;
  int carry = 0;
  for (int bb = 0; bb < NB; bb += 256) {
    int idx = bb + t;
    int v = (idx < NB) ? rowsum[idx] : 0;
    sc[t] = v;
    __syncthreads();
    #pragma unroll
    for (int off = 1; off < 256; off <<= 1) {
      int tmp = (t >= off) ? sc[t - off] : 0;
      __syncthreads();
      sc[t] += tmp;
      __syncthreads();
    }
    if (idx < NB) lcur[idx] = sc[t] - v + carry + rowscan[(size_t)idx * NCHUNK + g];
    carry += sc[255];
    __syncthreads();
  }
  __syncthreads();
  int C = (E + NCHUNK - 1) / NCHUNK;
  int e0 = g * C, e1 = min(E, e0 + C);
  for (int e = e0 + t; e < e1; e += 256) {
    int s = ei[e];
    int d = ei[E + e];
    int b = d >> BSH;
    int pos = atomicAdd(&lcur[b], 1);
    part[pos] = (unsigned)s | ((unsigned)(d & (BNODES - 1)) << 23);
  }
}

// per-bucket CSR build; writes csr (node-sorted), rowoff, dinv
__global__ __launch_bounds__(256) void k_csrb(const unsigned* __restrict__ part,
                                              const int* __restrict__ rowsum,
                                              int* __restrict__ csr,
                                              int* __restrict__ rowoff,
                                              float* __restrict__ dinv,
                                              int n, int NB) {
  __shared__ int sc[256];
  __shared__ int lhist[BNODES];
  __shared__ int lro[BNODES];
  __shared__ int lcur[BNODES];
  __shared__ int lcsr[BCAP];
  int b = blockIdx.x;
  int t = threadIdx.x;
  int base = b << BSH;

  int partial = 0;
  for (int i = t; i < b; i += 256) partial += rowsum[i];
  sc[t] = partial;
  __syncthreads();
  #pragma unroll
  for (int off = 128; off > 0; off >>= 1) {
    if (t < off) sc[t] += sc[t + off];
    __syncthreads();
  }
  int bo = sc[0];
  int cnt = rowsum[b];
  __syncthreads();

  for (int i = t; i < BNODES; i += 256) lhist[i] = 0;
  __syncthreads();
  const unsigned* pp = part + bo;
  for (int j = t; j < cnt; j += 256) atomicAdd(&lhist[pp[j] >> 23], 1);
  __syncthreads();

  int v0 = lhist[t];
  sc[t] = v0;
  __syncthreads();
  #pragma unroll
  for (int off = 1; off < 256; off <<= 1) {
    int tmp = (t >= off) ? sc[t - off] : 0;
    __syncthreads();
    sc[t] += tmp;
    __syncthreads();
  }
  lro[t] = sc[t] - v0;
  int tot0 = sc[255];
  __syncthreads();
  int v1 = lhist[256 + t];
  sc[t] = v1;
  __syncthreads();
  #pragma unroll
  for (int off = 1; off < 256; off <<= 1) {
    int tmp = (t >= off) ? sc[t - off] : 0;
    __syncthreads();
    sc[t] += tmp;
    __syncthreads();
  }
  lro[256 + t] = sc[t] - v1 + tot0;
  __syncthreads();

  for (int i = t; i < BNODES; i += 256) {
    int v = base + i;
    if (v < n) {
      rowoff[v] = bo + lro[i];
      dinv[v] = rsqrtf((float)(lhist[i] + 1));
    }
    lcur[i] = 0;
  }
  if (t == 0 && base + BNODES >= n) rowoff[n] = bo + cnt;
  __syncthreads();

  if (cnt <= BCAP) {
    for (int j = t; j < cnt; j += 256) {
      unsigned pk = pp[j];
      int dl = (int)(pk >> 23);
      int pos = atomicAdd(&lcur[dl], 1);
      lcsr[lro[dl] + pos] = (int)(pk & 0x7FFFFFu);
    }
    __syncthreads();
    for (int j = t; j < cnt; j += 256) csr[bo + j] = lcsr[j];
  } else {
    for (int j = t; j < cnt; j += 256) {
      unsigned pk = pp[j];
      int dl = (int)(pk >> 23);
      int pos = atomicAdd(&lcur[dl], 1);
      csr[bo + lro[dl] + pos] = (int)(pk & 0x7FFFFFu);
    }
  }
}

// GEMM1 via MFMA: P1[n][64] (fp8 e4m3) = dinv[n] * (x[n] @ W1)
__global__ __launch_bounds__(256) void k_gemm1(const float* __restrict__ x,
                                               const bf16_t* __restrict__ w1t,
                                               const float* __restrict__ dinv,
                                               unsigned char* __restrict__ P1, int n) {
  int t = threadIdx.x;
  int w = t >> 6, l = t & 63;
  int rowBase = blockIdx.x * 64 + w * 16;
  int fr = l & 15, fk = l >> 4;
  int ar = rowBase + fr; if (ar >= n) ar = n - 1;
  const float* xp = x + (size_t)ar * FIN + fk * 8;
  const bf16_t* wb = w1t + (size_t)fr * FIN + fk * 8;

  f32x4 acc0 = {0.f, 0.f, 0.f, 0.f};
  f32x4 acc1 = {0.f, 0.f, 0.f, 0.f};
  f32x4 acc2 = {0.f, 0.f, 0.f, 0.f};
  f32x4 acc3 = {0.f, 0.f, 0.f, 0.f};

  #pragma unroll 4
  for (int kt = 0; kt < FIN; kt += 32) {
    float4 a0 = *(const float4*)(xp + kt);
    float4 a1 = *(const float4*)(xp + kt + 4);
    bf16x8 av;
    av[0] = (bf16_t)a0.x; av[1] = (bf16_t)a0.y; av[2] = (bf16_t)a0.z; av[3] = (bf16_t)a0.w;
    av[4] = (bf16_t)a1.x; av[5] = (bf16_t)a1.y; av[6] = (bf16_t)a1.z; av[7] = (bf16_t)a1.w;
    bf16x8 b0 = *(const bf16x8*)(wb + kt);
    bf16x8 b1 = *(const bf16x8*)(wb + (size_t)16 * FIN + kt);
    bf16x8 b2 = *(const bf16x8*)(wb + (size_t)32 * FIN + kt);
    bf16x8 b3 = *(const bf16x8*)(wb + (size_t)48 * FIN + kt);
    acc0 = __builtin_amdgcn_mfma_f32_16x16x32_bf16(av, b0, acc0, 0, 0, 0);
    acc1 = __builtin_amdgcn_mfma_f32_16x16x32_bf16(av, b1, acc1, 0, 0, 0);
    acc2 = __builtin_amdgcn_mfma_f32_16x16x32_bf16(av, b2, acc2, 0, 0, 0);
    acc3 = __builtin_amdgcn_mfma_f32_16x16x32_bf16(av, b3, acc3, 0, 0, 0);
  }

  #pragma unroll
  for (int rg = 0; rg < 4; rg++) {
    int grow = rowBase + fk * 4 + rg;
    if (grow < n) {
      float dv = dinv[grow];
      unsigned char* prow = P1 + (size_t)grow * FH + fr;
      prow[0]  = f32_to_fp8(dv * acc0[rg]);
      prow[16] = f32_to_fp8(dv * acc1[rg]);
      prow[32] = f32_to_fp8(dv * acc2[rg]);
      prow[48] = f32_to_fp8(dv * acc3[rg]);
    }
  }
}

// gather1 (fp8 rows, 64B): wave = 16 subgroups x 4 lanes x uint4; one node each.
__global__ __launch_bounds__(256) void k_gather1(const unsigned char* __restrict__ P1,
                                                 const int* __restrict__ csr,
                                                 const int* __restrict__ rowoff,
                                                 const float* __restrict__ dinv,
                                                 const float* __restrict__ b1,
                                                 bf16_t* __restrict__ h, int n) {
  int l = threadIdx.x & 63;
  int sg = l >> 2, dg = l & 3;    // lane covers dims dg*16 .. dg*16+15
  int wv = (blockIdx.x * 256 + threadIdx.x) >> 6;
  int v = wv * 16 + sg;
  if (v >= n) return;
  const uint4* P1v = (const uint4*)P1;
  int base = rowoff[v];
  int cnt = rowoff[v + 1] - base;

  float a[16], c[16];
  {
    uint4 r = P1v[(size_t)v * 4 + dg];  // self loop
    SET16(a, r);
    #pragma unroll
    for (int k = 0; k < 16; k++) c[k] = 0.f;
  }

  int cnt4 = cnt & ~3;
  int j = 0;
  for (; j < cnt4; j += 4) {
    int u0 = csr[base + j];
    int u1 = csr[base + j + 1];
    int u2 = csr[base + j + 2];
    int u3 = csr[base + j + 3];
    uint4 r0 = P1v[(size_t)u0 * 4 + dg];
    uint4 r1 = P1v[(size_t)u1 * 4 + dg];
    uint4 r2 = P1v[(size_t)u2 * 4 + dg];
    uint4 r3 = P1v[(size_t)u3 * 4 + dg];
    ACC16(a, r0);
    ACC16(c, r1);
    ACC16(a, r2);
    ACC16(c, r3);
  }
  for (; j < cnt; j++) {
    int u = csr[base + j];
    uint4 r = P1v[(size_t)u * 4 + dg];
    ACC16(a, r);
  }

  float dv = dinv[v];
  const float4* b1v = (const float4*)b1;
  bf16x8 hv0, hv1;
  #pragma unroll
  for (int q = 0; q < 4; q++) {
    float4 bb = b1v[dg * 4 + q];
    float s0 = fmaxf(dv * (a[q*4+0] + c[q*4+0]) + bb.x, 0.f);
    float s1 = fmaxf(dv * (a[q*4+1] + c[q*4+1]) + bb.y, 0.f);
    float s2 = fmaxf(dv * (a[q*4+2] + c[q*4+2]) + bb.z, 0.f);
    float s3 = fmaxf(dv * (a[q*4+3] + c[q*4+3]) + bb.w, 0.f);
    if (q < 2) {
      hv0[q*4+0] = (bf16_t)s0; hv0[q*4+1] = (bf16_t)s1;
      hv0[q*4+2] = (bf16_t)s2; hv0[q*4+3] = (bf16_t)s3;
    } else {
      hv1[(q-2)*4+0] = (bf16_t)s0; hv1[(q-2)*4+1] = (bf16_t)s1;
      hv1[(q-2)*4+2] = (bf16_t)s2; hv1[(q-2)*4+3] = (bf16_t)s3;
    }
  }
  ((bf16x8*)h)[(size_t)v * 8 + dg * 2]     = hv0;
  ((bf16x8*)h)[(size_t)v * 8 + dg * 2 + 1] = hv1;
}

// GEMM2 via MFMA: P2[n][32] (fp8 e4m3) = dinv[n] * (h[n] @ W2)
__global__ __launch_bounds__(256) void k_gemm2(const bf16_t* __restrict__ h,
                                               const bf16_t* __restrict__ w2t,
                                               const float* __restrict__ dinv,
                                               unsigned char* __restrict__ P2, int n) {
  int t = threadIdx.x;
  int w = t >> 6, l = t & 63;
  int rowBase = blockIdx.x * 64 + w * 16;
  int fr = l & 15, fk = l >> 4;
  int ar = rowBase + fr; if (ar >= n) ar = n - 1;
  const bf16_t* hp = h + (size_t)ar * FH + fk * 8;
  const bf16_t* wb0 = w2t + (size_t)fr * FH + fk * 8;
  const bf16_t* wb1 = w2t + (size_t)(fr + 16) * FH + fk * 8;

  f32x4 acc0 = {0.f, 0.f, 0.f, 0.f};
  f32x4 acc1 = {0.f, 0.f, 0.f, 0.f};
  #pragma unroll
  for (int kt = 0; kt < FH; kt += 32) {
    bf16x8 af = *(const bf16x8*)(hp + kt);
    bf16x8 b0 = *(const bf16x8*)(wb0 + kt);
    bf16x8 b1 = *(const bf16x8*)(wb1 + kt);
    acc0 = __builtin_amdgcn_mfma_f32_16x16x32_bf16(af, b0, acc0, 0, 0, 0);
    acc1 = __builtin_amdgcn_mfma_f32_16x16x32_bf16(af, b1, acc1, 0, 0, 0);
  }
  #pragma unroll
  for (int rg = 0; rg < 4; rg++) {
    int grow = rowBase + fk * 4 + rg;
    if (grow < n) {
      float dv = dinv[grow];
      unsigned char* prow = P2 + (size_t)grow * FO + fr;
      prow[0]  = f32_to_fp8(dv * acc0[rg]);
      prow[16] = f32_to_fp8(dv * acc1[rg]);
    }
  }
}

// gather2 + bias + log_softmax (fp8 rows, 32B): wave = 32 subgroups x 2 lanes.
// Each lane covers 16 dims (one uint4). 2 requests/edge. Softmax: 16 in-lane + xor(1).
__global__ __launch_bounds__(256) void k_g2final(const unsigned char* __restrict__ P2,
                                                 const int* __restrict__ csr,
                                                 const int* __restrict__ rowoff,
                                                 const float* __restrict__ dinv,
                                                 const float* __restrict__ b2,
                                                 float* __restrict__ out, int n) {
  int l = threadIdx.x & 63;
  int sg = l >> 1, dg = l & 1;   // lane covers dims dg*16 .. dg*16+15
  int wv = (blockIdx.x * 256 + threadIdx.x) >> 6;
  int v = wv * 32 + sg;
  if (v >= n) return;
  const uint4* P2v = (const uint4*)P2;  // row = 2 x uint4
  int base = rowoff[v];
  int cnt = rowoff[v + 1] - base;

  float a[16], c[16];
  {
    uint4 r = P2v[(size_t)v * 2 + dg];  // self loop
    SET16(a, r);
    #pragma unroll
    for (int k = 0; k < 16; k++) c[k] = 0.f;
  }

  int cnt4 = cnt & ~3;
  int j = 0;
  for (; j < cnt4; j += 4) {
    int u0 = csr[base + j];
    int u1 = csr[base + j + 1];
    int u2 = csr[base + j + 2];
    int u3 = csr[base + j + 3];
    uint4 r0 = P2v[(size_t)u0 * 2 + dg];
    uint4 r1 = P2v[(size_t)u1 * 2 + dg];
    uint4 r2 = P2v[(size_t)u2 * 2 + dg];
    uint4 r3 = P2v[(size_t)u3 * 2 + dg];
    ACC16(a, r0);
    ACC16(c, r1);
    ACC16(a, r2);
    ACC16(c, r3);
  }
  for (; j < cnt; j++) {
    int u = csr[base + j];
    uint4 r = P2v[(size_t)u * 2 + dg];
    ACC16(a, r);
  }

  float dv = dinv[v];
  const float4* b2v = (const float4*)b2;
  float val[16];
  #pragma unroll
  for (int q = 0; q < 4; q++) {
    float4 bb = b2v[dg * 4 + q];
    val[q*4+0] = dv * (a[q*4+0] + c[q*4+0]) + bb.x;
    val[q*4+1] = dv * (a[q*4+1] + c[q*4+1]) + bb.y;
    val[q*4+2] = dv * (a[q*4+2] + c[q*4+2]) + bb.z;
    val[q*4+3] = dv * (a[q*4+3] + c[q*4+3]) + bb.w;
  }
  float m = val[0];
  #pragma unroll
  for (int q = 1; q < 16; q++) m = fmaxf(m, val[q]);
  m = fmaxf(m, __shfl_xor(m, 1, 64));
  float se = 0.f;
  #pragma unroll
  for (int q = 0; q < 16; q++) se += expf(val[q] - m);
  se += __shfl_xor(se, 1, 64);
  float lse = m + logf(se);
  float* orow = out + (size_t)v * FO + dg * 16;
  #pragma unroll
  for (int q = 0; q < 4; q++) {
    float4 o;
    o.x = val[q*4+0] - lse; o.y = val[q*4+1] - lse;
    o.z = val[q*4+2] - lse; o.w = val[q*4+3] - lse;
    *(float4*)(orow + q * 4) = o;
  }
}

extern "C" void kernel_launch(void* const* d_in, const int* in_sizes, int n_in,
                              void* d_out, int out_size, void* d_ws, size_t ws_size,
                              hipStream_t stream) {
  const float* x  = (const float*)d_in[0];
  const int*   ei = (const int*)d_in[1];
  const float* W1 = (const float*)d_in[2];
  const float* b1 = (const float*)d_in[3];
  const float* W2 = (const float*)d_in[4];
  const float* b2 = (const float*)d_in[5];
  const int N = in_sizes[0] / FIN;
  const int E = in_sizes[1] / 2;
  float* out = (float*)d_out;

  size_t NP = ((size_t)N + 63) & ~(size_t)63;
  size_t EP = ((size_t)E + 63) & ~(size_t)63;
  int NB = (N + BNODES - 1) >> BSH;

  int*           histmat = (int*)d_ws;                        // NBMAX*NCHUNK
  int*           rowscan = histmat + (size_t)NBMAX * NCHUNK;  // NBMAX*NCHUNK
  int*           rowsum  = rowscan + (size_t)NBMAX * NCHUNK;  // NBMAX
  int*           rowoff  = rowsum + NBMAX;                    // NP+64 (incl sentinel)
  float*         dinv    = (float*)(rowoff + NP + 64);        // NP
  int*           csr     = (int*)(dinv + NP);                 // EP
  unsigned*      part    = (unsigned*)(csr + EP);             // EP
  bf16_t*        w1t     = (bf16_t*)(part + EP);              // 64*512
  bf16_t*        w2t     = w1t + (size_t)FH * FIN;            // 32*64
  unsigned char* P1      = (unsigned char*)(w2t + (size_t)FO * FH);  // NP*64 bytes
  bf16_t*        h       = (bf16_t*)(P1 + NP * FH);           // NP*64
  unsigned char* P2      = (unsigned char*)(h + NP * FH);     // NP*32 bytes

  int wconvB = (FIN * FH + 255) / 256;  // 128 rider blocks
  k_histA<<<NCHUNK + wconvB, 256, 0, stream>>>(ei + E, histmat, E, NB, W1, w1t, W2, w2t);
  k_scanB<<<NB, 256, 0, stream>>>(histmat, rowscan, rowsum, NB);
  k_scatC<<<NCHUNK, 256, 0, stream>>>(ei, rowscan, rowsum, part, E, NB);
  k_csrb<<<NB, 256, 0, stream>>>(part, rowsum, csr, rowoff, dinv, N, NB);
  k_gemm1<<<(N + 63) / 64, 256, 0, stream>>>(x, w1t, dinv, P1, N);
  {
    int waves = (N + 15) / 16;
    k_gather1<<<(waves + 3) / 4, 256, 0, stream>>>(P1, csr, rowoff, dinv, b1, h, N);
  }
  k_gemm2<<<(N + 63) / 64, 256, 0, stream>>>(h, w2t, dinv, P2, N);
  {
    int waves = (N + 31) / 32;
    k_g2final<<<(waves + 3) / 4, 256, 0, stream>>>(P2, csr, rowoff, dinv, b2, out, N);
  }
}

// Round 15
// 184.512 us; speedup vs baseline: 6.6203x; 1.0135x over previous
//
#include <hip/hip_runtime.h>
#include <math.h>

#define FIN 512
#define FH  64
#define FO  32

#define BSH    8          // 256 nodes per dst-bucket
#define BNODES 256
#define NCHUNK 1024       // radix chunk-blocks (4/CU)
#define BCAP   6144       // LDS csr capacity per bucket (mean 4096, sigma ~64)
#define NBMAX  512

typedef __bf16 bf16_t;
typedef bf16_t bf16x8 __attribute__((ext_vector_type(8)));
typedef float  f32x4  __attribute__((ext_vector_type(4)));
typedef float  f32x2  __attribute__((ext_vector_type(2)));

__device__ __forceinline__ unsigned char f32_to_fp8(float v) {
  int p = __builtin_amdgcn_cvt_pk_fp8_f32(v, v, 0, false);
  return (unsigned char)(p & 0xff);
}

// decode 16 fp8 (one uint4) and accumulate into dst[16]
#define ACC16(dst, r) { \
  f32x2 d0 = __builtin_amdgcn_cvt_pk_f32_fp8((int)(r).x, false); \
  f32x2 d1 = __builtin_amdgcn_cvt_pk_f32_fp8((int)(r).x, true);  \
  f32x2 d2 = __builtin_amdgcn_cvt_pk_f32_fp8((int)(r).y, false); \
  f32x2 d3 = __builtin_amdgcn_cvt_pk_f32_fp8((int)(r).y, true);  \
  f32x2 d4 = __builtin_amdgcn_cvt_pk_f32_fp8((int)(r).z, false); \
  f32x2 d5 = __builtin_amdgcn_cvt_pk_f32_fp8((int)(r).z, true);  \
  f32x2 d6 = __builtin_amdgcn_cvt_pk_f32_fp8((int)(r).w, false); \
  f32x2 d7 = __builtin_amdgcn_cvt_pk_f32_fp8((int)(r).w, true);  \
  dst[0] += d0[0]; dst[1] += d0[1]; dst[2] += d1[0]; dst[3] += d1[1]; \
  dst[4] += d2[0]; dst[5] += d2[1]; dst[6] += d3[0]; dst[7] += d3[1]; \
  dst[8] += d4[0]; dst[9] += d4[1]; dst[10] += d5[0]; dst[11] += d5[1]; \
  dst[12] += d6[0]; dst[13] += d6[1]; dst[14] += d7[0]; dst[15] += d7[1]; }

#define SET16(dst, r) { \
  f32x2 d0 = __builtin_amdgcn_cvt_pk_f32_fp8((int)(r).x, false); \
  f32x2 d1 = __builtin_amdgcn_cvt_pk_f32_fp8((int)(r).x, true);  \
  f32x2 d2 = __builtin_amdgcn_cvt_pk_f32_fp8((int)(r).y, false); \
  f32x2 d3 = __builtin_amdgcn_cvt_pk_f32_fp8((int)(r).y, true);  \
  f32x2 d4 = __builtin_amdgcn_cvt_pk_f32_fp8((int)(r).z, false); \
  f32x2 d5 = __builtin_amdgcn_cvt_pk_f32_fp8((int)(r).z, true);  \
  f32x2 d6 = __builtin_amdgcn_cvt_pk_f32_fp8((int)(r).w, false); \
  f32x2 d7 = __builtin_amdgcn_cvt_pk_f32_fp8((int)(r).w, true);  \
  dst[0] = d0[0]; dst[1] = d0[1]; dst[2] = d1[0]; dst[3] = d1[1]; \
  dst[4] = d2[0]; dst[5] = d2[1]; dst[6] = d3[0]; dst[7] = d3[1]; \
  dst[8] = d4[0]; dst[9] = d4[1]; dst[10] = d5[0]; dst[11] = d5[1]; \
  dst[12] = d6[0]; dst[13] = d6[1]; dst[14] = d7[0]; dst[15] = d7[1]; }

// radix pass A + weight-convert riders
__global__ __launch_bounds__(256) void k_histA(const int* __restrict__ dst,
                                               int* __restrict__ histmat,
                                               int E, int NB,
                                               const float* __restrict__ W1,
                                               bf16_t* __restrict__ w1t,
                                               const float* __restrict__ W2,
                                               bf16_t* __restrict__ w2t) {
  if (blockIdx.x >= NCHUNK) {
    int i = (blockIdx.x - NCHUNK) * 256 + threadIdx.x;
    if (i < FIN * FH) {
      int c = i >> 9, k = i & 511;
      w1t[i] = (bf16_t)W1[(size_t)k * FH + c];
    }
    if (i < FH * FO) {
      int c = i >> 6, k = i & 63;
      w2t[i] = (bf16_t)W2[(size_t)k * FO + c];
    }
    return;
  }
  __shared__ int lh[NBMAX];
  int t = threadIdx.x;
  int g = blockIdx.x;
  for (int i = t; i < NB; i += 256) lh[i] = 0;
  __syncthreads();
  int C = (E + NCHUNK - 1) / NCHUNK;
  int e0 = g * C, e1 = min(E, e0 + C);
  for (int e = e0 + t; e < e1; e += 256) {
    atomicAdd(&lh[dst[e] >> BSH], 1);
  }
  __syncthreads();
  for (int b = t; b < NB; b += 256) histmat[(size_t)b * NCHUNK + g] = lh[b];
}

// radix pass B: per-bucket exclusive scan over NCHUNK chunks (4 rounds of 256)
__global__ __launch_bounds__(256) void k_scanB(const int* __restrict__ histmat,
                                               int* __restrict__ rowscan,
                                               int* __restrict__ rowsum, int NB) {
  __shared__ int s[256];
  int b = blockIdx.x;
  int t = threadIdx.x;
  int carry = 0;
  for (int r = 0; r < NCHUNK; r += 256) {
    int v = histmat[(size_t)b * NCHUNK + r + t];
    s[t] = v;
    __syncthreads();
    #pragma unroll
    for (int off = 1; off < 256; off <<= 1) {
      int tmp = (t >= off) ? s[t - off] : 0;
      __syncthreads();
      s[t] += tmp;
      __syncthreads();
    }
    rowscan[(size_t)b * NCHUNK + r + t] = s[t] - v + carry;
    carry += s[255];
    __syncthreads();
  }
  if (t == 0) rowsum[b] = carry;
}

// radix pass C: scatter packed (dlocal<<23 | src) into bucket-grouped part[]
__global__ __launch_bounds__(256) void k_scatC(const int* __restrict__ ei,
                                               const int* __restrict__ rowscan,
                                               const int* __restrict__ rowsum,
                                               unsigned* __restrict__ part,
                                               int E, int NB) {
  __shared__ int lcur[NBMAX];
  __shared__ int sc[256];
  int t = threadIdx.x;
  int g = blockIdx.x;
  int carry = 0;
  for (int bb = 0; bb < NB; bb += 256) {
    int idx = bb + t;
    int v = (idx < NB) ? rowsum[idx] : 0;
    sc[t] = v;
    __syncthreads();
    #pragma unroll
    for (int off = 1; off < 256; off <<= 1) {
      int tmp = (t >= off) ? sc[t - off] : 0;
      __syncthreads();
      sc[t] += tmp;
      __syncthreads();
    }
    if (idx < NB) lcur[idx] = sc[t] - v + carry + rowscan[(size_t)idx * NCHUNK + g];
    carry += sc[255];
    __syncthreads();
  }
  __syncthreads();
  int C = (E + NCHUNK - 1) / NCHUNK;
  int e0 = g * C, e1 = min(E, e0 + C);
  for (int e = e0 + t; e < e1; e += 256) {
    int s = ei[e];
    int d = ei[E + e];
    int b = d >> BSH;
    int pos = atomicAdd(&lcur[b], 1);
    part[pos] = (unsigned)s | ((unsigned)(d & (BNODES - 1)) << 23);
  }
}

// per-bucket CSR build; writes csr (node-sorted), rowoff, dinv
__global__ __launch_bounds__(256) void k_csrb(const unsigned* __restrict__ part,
                                              const int* __restrict__ rowsum,
                                              int* __restrict__ csr,
                                              int* __restrict__ rowoff,
                                              float* __restrict__ dinv,
                                              int n, int NB) {
  __shared__ int sc[256];
  __shared__ int lhist[BNODES];
  __shared__ int lro[BNODES];
  __shared__ int lcur[BNODES];
  __shared__ int lcsr[BCAP];
  int b = blockIdx.x;
  int t = threadIdx.x;
  int base = b << BSH;

  // bo = sum(rowsum[0..b))
  int partial = 0;
  for (int i = t; i < b; i += 256) partial += rowsum[i];
  sc[t] = partial;
  __syncthreads();
  #pragma unroll
  for (int off = 128; off > 0; off >>= 1) {
    if (t < off) sc[t] += sc[t + off];
    __syncthreads();
  }
  int bo = sc[0];
  int cnt = rowsum[b];
  __syncthreads();

  lhist[t] = 0;
  __syncthreads();
  const unsigned* pp = part + bo;
  for (int j = t; j < cnt; j += 256) atomicAdd(&lhist[pp[j] >> 23], 1);
  __syncthreads();

  int v0 = lhist[t];
  sc[t] = v0;
  __syncthreads();
  #pragma unroll
  for (int off = 1; off < 256; off <<= 1) {
    int tmp = (t >= off) ? sc[t - off] : 0;
    __syncthreads();
    sc[t] += tmp;
    __syncthreads();
  }
  lro[t] = sc[t] - v0;
  __syncthreads();

  {
    int v = base + t;
    if (v < n) {
      rowoff[v] = bo + lro[t];
      dinv[v] = rsqrtf((float)(lhist[t] + 1));
    }
    lcur[t] = 0;
    if (t == 0 && base + BNODES >= n) rowoff[n] = bo + cnt;
  }
  __syncthreads();

  if (cnt <= BCAP) {
    for (int j = t; j < cnt; j += 256) {
      unsigned pk = pp[j];
      int dl = (int)(pk >> 23);
      int pos = atomicAdd(&lcur[dl], 1);
      lcsr[lro[dl] + pos] = (int)(pk & 0x7FFFFFu);
    }
    __syncthreads();
    for (int j = t; j < cnt; j += 256) csr[bo + j] = lcsr[j];
  } else {
    for (int j = t; j < cnt; j += 256) {
      unsigned pk = pp[j];
      int dl = (int)(pk >> 23);
      int pos = atomicAdd(&lcur[dl], 1);
      csr[bo + lro[dl] + pos] = (int)(pk & 0x7FFFFFu);
    }
  }
}

// GEMM1 via MFMA: P1[n][64] (fp8 e4m3) = dinv[n] * (x[n] @ W1)
__global__ __launch_bounds__(256) void k_gemm1(const float* __restrict__ x,
                                               const bf16_t* __restrict__ w1t,
                                               const float* __restrict__ dinv,
                                               unsigned char* __restrict__ P1, int n) {
  int t = threadIdx.x;
  int w = t >> 6, l = t & 63;
  int rowBase = blockIdx.x * 64 + w * 16;
  int fr = l & 15, fk = l >> 4;
  int ar = rowBase + fr; if (ar >= n) ar = n - 1;
  const float* xp = x + (size_t)ar * FIN + fk * 8;
  const bf16_t* wb = w1t + (size_t)fr * FIN + fk * 8;

  f32x4 acc0 = {0.f, 0.f, 0.f, 0.f};
  f32x4 acc1 = {0.f, 0.f, 0.f, 0.f};
  f32x4 acc2 = {0.f, 0.f, 0.f, 0.f};
  f32x4 acc3 = {0.f, 0.f, 0.f, 0.f};

  #pragma unroll 4
  for (int kt = 0; kt < FIN; kt += 32) {
    float4 a0 = *(const float4*)(xp + kt);
    float4 a1 = *(const float4*)(xp + kt + 4);
    bf16x8 av;
    av[0] = (bf16_t)a0.x; av[1] = (bf16_t)a0.y; av[2] = (bf16_t)a0.z; av[3] = (bf16_t)a0.w;
    av[4] = (bf16_t)a1.x; av[5] = (bf16_t)a1.y; av[6] = (bf16_t)a1.z; av[7] = (bf16_t)a1.w;
    bf16x8 b0 = *(const bf16x8*)(wb + kt);
    bf16x8 b1 = *(const bf16x8*)(wb + (size_t)16 * FIN + kt);
    bf16x8 b2 = *(const bf16x8*)(wb + (size_t)32 * FIN + kt);
    bf16x8 b3 = *(const bf16x8*)(wb + (size_t)48 * FIN + kt);
    acc0 = __builtin_amdgcn_mfma_f32_16x16x32_bf16(av, b0, acc0, 0, 0, 0);
    acc1 = __builtin_amdgcn_mfma_f32_16x16x32_bf16(av, b1, acc1, 0, 0, 0);
    acc2 = __builtin_amdgcn_mfma_f32_16x16x32_bf16(av, b2, acc2, 0, 0, 0);
    acc3 = __builtin_amdgcn_mfma_f32_16x16x32_bf16(av, b3, acc3, 0, 0, 0);
  }

  #pragma unroll
  for (int rg = 0; rg < 4; rg++) {
    int grow = rowBase + fk * 4 + rg;
    if (grow < n) {
      float dv = dinv[grow];
      unsigned char* prow = P1 + (size_t)grow * FH + fr;
      prow[0]  = f32_to_fp8(dv * acc0[rg]);
      prow[16] = f32_to_fp8(dv * acc1[rg]);
      prow[32] = f32_to_fp8(dv * acc2[rg]);
      prow[48] = f32_to_fp8(dv * acc3[rg]);
    }
  }
}

// FUSED gather1 + gemm2: block = 64 nodes (4 waves x 16).
// Phase 1 (gather): wave = 16 subgroups x 4 lanes x uint4 over fp8 P1 rows;
//   h = relu(dinv*sum + b1) -> LDS [64][72] bf16 (padded, 2-way banks max).
// Phase 2 (gemm2 MFMA from LDS): P2[n][32] fp8 = dinv * (h @ W2).
__global__ __launch_bounds__(256) void k_g1g2(const unsigned char* __restrict__ P1,
                                              const int* __restrict__ csr,
                                              const int* __restrict__ rowoff,
                                              const float* __restrict__ dinv,
                                              const float* __restrict__ b1,
                                              const bf16_t* __restrict__ w2t,
                                              unsigned char* __restrict__ P2, int n) {
  __shared__ bf16_t hl[64][72];
  int t = threadIdx.x;
  int w = t >> 6, l = t & 63;
  int sg = l >> 2, dg = l & 3;      // lane covers dims dg*16..dg*16+15
  int nl = w * 16 + sg;             // node-local 0..63
  int v = blockIdx.x * 64 + nl;
  bool act = v < n;

  bf16x8 hv0 = {};
  bf16x8 hv1 = {};
  if (act) {
    const uint4* P1v = (const uint4*)P1;
    int base = rowoff[v];
    int cnt = rowoff[v + 1] - base;
    float a[16], c[16];
    {
      uint4 r = P1v[(size_t)v * 4 + dg];  // self loop
      SET16(a, r);
      #pragma unroll
      for (int k = 0; k < 16; k++) c[k] = 0.f;
    }
    int cnt4 = cnt & ~3;
    int j = 0;
    for (; j < cnt4; j += 4) {
      int u0 = csr[base + j];
      int u1 = csr[base + j + 1];
      int u2 = csr[base + j + 2];
      int u3 = csr[base + j + 3];
      uint4 r0 = P1v[(size_t)u0 * 4 + dg];
      uint4 r1 = P1v[(size_t)u1 * 4 + dg];
      uint4 r2 = P1v[(size_t)u2 * 4 + dg];
      uint4 r3 = P1v[(size_t)u3 * 4 + dg];
      ACC16(a, r0);
      ACC16(c, r1);
      ACC16(a, r2);
      ACC16(c, r3);
    }
    for (; j < cnt; j++) {
      int u = csr[base + j];
      uint4 r = P1v[(size_t)u * 4 + dg];
      ACC16(a, r);
    }
    float dv = dinv[v];
    const float4* b1v = (const float4*)b1;
    #pragma unroll
    for (int q = 0; q < 4; q++) {
      float4 bb = b1v[dg * 4 + q];
      float s0 = fmaxf(dv * (a[q*4+0] + c[q*4+0]) + bb.x, 0.f);
      float s1 = fmaxf(dv * (a[q*4+1] + c[q*4+1]) + bb.y, 0.f);
      float s2 = fmaxf(dv * (a[q*4+2] + c[q*4+2]) + bb.z, 0.f);
      float s3 = fmaxf(dv * (a[q*4+3] + c[q*4+3]) + bb.w, 0.f);
      if (q < 2) {
        hv0[q*4+0] = (bf16_t)s0; hv0[q*4+1] = (bf16_t)s1;
        hv0[q*4+2] = (bf16_t)s2; hv0[q*4+3] = (bf16_t)s3;
      } else {
        hv1[(q-2)*4+0] = (bf16_t)s0; hv1[(q-2)*4+1] = (bf16_t)s1;
        hv1[(q-2)*4+2] = (bf16_t)s2; hv1[(q-2)*4+3] = (bf16_t)s3;
      }
    }
  }
  *(bf16x8*)&hl[nl][dg * 16]     = hv0;
  *(bf16x8*)&hl[nl][dg * 16 + 8] = hv1;
  __syncthreads();

  // gemm2 from LDS: wave w handles local rows w*16..w*16+15
  int fr = l & 15, fk = l >> 4;
  f32x4 acc0 = {0.f, 0.f, 0.f, 0.f};
  f32x4 acc1 = {0.f, 0.f, 0.f, 0.f};
  const bf16_t* wb0 = w2t + (size_t)fr * FH + fk * 8;
  const bf16_t* wb1 = w2t + (size_t)(fr + 16) * FH + fk * 8;
  #pragma unroll
  for (int kt = 0; kt < FH; kt += 32) {
    bf16x8 af = *(const bf16x8*)&hl[w * 16 + fr][kt + fk * 8];
    bf16x8 b0 = *(const bf16x8*)(wb0 + kt);
    bf16x8 b1v_ = *(const bf16x8*)(wb1 + kt);
    acc0 = __builtin_amdgcn_mfma_f32_16x16x32_bf16(af, b0, acc0, 0, 0, 0);
    acc1 = __builtin_amdgcn_mfma_f32_16x16x32_bf16(af, b1v_, acc1, 0, 0, 0);
  }
  #pragma unroll
  for (int rg = 0; rg < 4; rg++) {
    int grow = blockIdx.x * 64 + w * 16 + fk * 4 + rg;
    if (grow < n) {
      float dv = dinv[grow];
      unsigned char* prow = P2 + (size_t)grow * FO + fr;
      prow[0]  = f32_to_fp8(dv * acc0[rg]);
      prow[16] = f32_to_fp8(dv * acc1[rg]);
    }
  }
}

// gather2 + bias + log_softmax (fp8 rows, 32B): wave = 32 subgroups x 2 lanes.
__global__ __launch_bounds__(256) void k_g2final(const unsigned char* __restrict__ P2,
                                                 const int* __restrict__ csr,
                                                 const int* __restrict__ rowoff,
                                                 const float* __restrict__ dinv,
                                                 const float* __restrict__ b2,
                                                 float* __restrict__ out, int n) {
  int l = threadIdx.x & 63;
  int sg = l >> 1, dg = l & 1;   // lane covers dims dg*16 .. dg*16+15
  int wv = (blockIdx.x * 256 + threadIdx.x) >> 6;
  int v = wv * 32 + sg;
  if (v >= n) return;
  const uint4* P2v = (const uint4*)P2;  // row = 2 x uint4
  int base = rowoff[v];
  int cnt = rowoff[v + 1] - base;

  float a[16], c[16];
  {
    uint4 r = P2v[(size_t)v * 2 + dg];  // self loop
    SET16(a, r);
    #pragma unroll
    for (int k = 0; k < 16; k++) c[k] = 0.f;
  }

  int cnt4 = cnt & ~3;
  int j = 0;
  for (; j < cnt4; j += 4) {
    int u0 = csr[base + j];
    int u1 = csr[base + j + 1];
    int u2 = csr[base + j + 2];
    int u3 = csr[base + j + 3];
    uint4 r0 = P2v[(size_t)u0 * 2 + dg];
    uint4 r1 = P2v[(size_t)u1 * 2 + dg];
    uint4 r2 = P2v[(size_t)u2 * 2 + dg];
    uint4 r3 = P2v[(size_t)u3 * 2 + dg];
    ACC16(a, r0);
    ACC16(c, r1);
    ACC16(a, r2);
    ACC16(c, r3);
  }
  for (; j < cnt; j++) {
    int u = csr[base + j];
    uint4 r = P2v[(size_t)u * 2 + dg];
    ACC16(a, r);
  }

  float dv = dinv[v];
  const float4* b2v = (const float4*)b2;
  float val[16];
  #pragma unroll
  for (int q = 0; q < 4; q++) {
    float4 bb = b2v[dg * 4 + q];
    val[q*4+0] = dv * (a[q*4+0] + c[q*4+0]) + bb.x;
    val[q*4+1] = dv * (a[q*4+1] + c[q*4+1]) + bb.y;
    val[q*4+2] = dv * (a[q*4+2] + c[q*4+2]) + bb.z;
    val[q*4+3] = dv * (a[q*4+3] + c[q*4+3]) + bb.w;
  }
  float m = val[0];
  #pragma unroll
  for (int q = 1; q < 16; q++) m = fmaxf(m, val[q]);
  m = fmaxf(m, __shfl_xor(m, 1, 64));
  float se = 0.f;
  #pragma unroll
  for (int q = 0; q < 16; q++) se += expf(val[q] - m);
  se += __shfl_xor(se, 1, 64);
  float lse = m + logf(se);
  float* orow = out + (size_t)v * FO + dg * 16;
  #pragma unroll
  for (int q = 0; q < 4; q++) {
    float4 o;
    o.x = val[q*4+0] - lse; o.y = val[q*4+1] - lse;
    o.z = val[q*4+2] - lse; o.w = val[q*4+3] - lse;
    *(float4*)(orow + q * 4) = o;
  }
}

extern "C" void kernel_launch(void* const* d_in, const int* in_sizes, int n_in,
                              void* d_out, int out_size, void* d_ws, size_t ws_size,
                              hipStream_t stream) {
  const float* x  = (const float*)d_in[0];
  const int*   ei = (const int*)d_in[1];
  const float* W1 = (const float*)d_in[2];
  const float* b1 = (const float*)d_in[3];
  const float* W2 = (const float*)d_in[4];
  const float* b2 = (const float*)d_in[5];
  const int N = in_sizes[0] / FIN;
  const int E = in_sizes[1] / 2;
  float* out = (float*)d_out;

  size_t NP = ((size_t)N + 63) & ~(size_t)63;
  size_t EP = ((size_t)E + 63) & ~(size_t)63;
  int NB = (N + BNODES - 1) >> BSH;

  int*           histmat = (int*)d_ws;                        // NBMAX*NCHUNK
  int*           rowscan = histmat + (size_t)NBMAX * NCHUNK;  // NBMAX*NCHUNK
  int*           rowsum  = rowscan + (size_t)NBMAX * NCHUNK;  // NBMAX
  int*           rowoff  = rowsum + NBMAX;                    // NP+64 (incl sentinel)
  float*         dinv    = (float*)(rowoff + NP + 64);        // NP
  int*           csr     = (int*)(dinv + NP);                 // EP
  unsigned*      part    = (unsigned*)(csr + EP);             // EP
  bf16_t*        w1t     = (bf16_t*)(part + EP);              // 64*512
  bf16_t*        w2t     = w1t + (size_t)FH * FIN;            // 32*64
  unsigned char* P1      = (unsigned char*)(w2t + (size_t)FO * FH);  // NP*64 bytes
  unsigned char* P2      = P1 + NP * FH;                      // NP*32 bytes

  int wconvB = (FIN * FH + 255) / 256;  // 128 rider blocks
  k_histA<<<NCHUNK + wconvB, 256, 0, stream>>>(ei + E, histmat, E, NB, W1, w1t, W2, w2t);
  k_scanB<<<NB, 256, 0, stream>>>(histmat, rowscan, rowsum, NB);
  k_scatC<<<NCHUNK, 256, 0, stream>>>(ei, rowscan, rowsum, part, E, NB);
  k_csrb<<<NB, 256, 0, stream>>>(part, rowsum, csr, rowoff, dinv, N, NB);
  k_gemm1<<<(N + 63) / 64, 256, 0, stream>>>(x, w1t, dinv, P1, N);
  k_g1g2<<<(N + 63) / 64, 256, 0, stream>>>(P1, csr, rowoff, dinv, b1, w2t, P2, N);
  {
    int waves = (N + 31) / 32;
    k_g2final<<<(waves + 3) / 4, 256, 0, stream>>>(P2, csr, rowoff, dinv, b2, out, N);
  }
}

// Round 16
// 176.507 us; speedup vs baseline: 6.9205x; 1.0454x over previous
//
#include <hip/hip_runtime.h>
#include <math.h>

#define FIN 512
#define FH  64
#define FO  32

#define BSH    8          // 256 nodes per dst-bucket
#define BNODES 256
#define NCHUNK 256        // radix chunk-blocks (full-line part[] runs: ~16 edges/bucket/chunk)
#define BCAP   6144       // LDS csr capacity per bucket (mean 4096, sigma ~64)
#define NBMAX  512

typedef __bf16 bf16_t;
typedef bf16_t bf16x8 __attribute__((ext_vector_type(8)));
typedef float  f32x4  __attribute__((ext_vector_type(4)));
typedef float  f32x2  __attribute__((ext_vector_type(2)));

__device__ __forceinline__ unsigned char f32_to_fp8(float v) {
  int p = __builtin_amdgcn_cvt_pk_fp8_f32(v, v, 0, false);
  return (unsigned char)(p & 0xff);
}

// decode 16 fp8 (one uint4) and accumulate into dst[16]
#define ACC16(dst, r) { \
  f32x2 d0 = __builtin_amdgcn_cvt_pk_f32_fp8((int)(r).x, false); \
  f32x2 d1 = __builtin_amdgcn_cvt_pk_f32_fp8((int)(r).x, true);  \
  f32x2 d2 = __builtin_amdgcn_cvt_pk_f32_fp8((int)(r).y, false); \
  f32x2 d3 = __builtin_amdgcn_cvt_pk_f32_fp8((int)(r).y, true);  \
  f32x2 d4 = __builtin_amdgcn_cvt_pk_f32_fp8((int)(r).z, false); \
  f32x2 d5 = __builtin_amdgcn_cvt_pk_f32_fp8((int)(r).z, true);  \
  f32x2 d6 = __builtin_amdgcn_cvt_pk_f32_fp8((int)(r).w, false); \
  f32x2 d7 = __builtin_amdgcn_cvt_pk_f32_fp8((int)(r).w, true);  \
  dst[0] += d0[0]; dst[1] += d0[1]; dst[2] += d1[0]; dst[3] += d1[1]; \
  dst[4] += d2[0]; dst[5] += d2[1]; dst[6] += d3[0]; dst[7] += d3[1]; \
  dst[8] += d4[0]; dst[9] += d4[1]; dst[10] += d5[0]; dst[11] += d5[1]; \
  dst[12] += d6[0]; dst[13] += d6[1]; dst[14] += d7[0]; dst[15] += d7[1]; }

#define SET16(dst, r) { \
  f32x2 d0 = __builtin_amdgcn_cvt_pk_f32_fp8((int)(r).x, false); \
  f32x2 d1 = __builtin_amdgcn_cvt_pk_f32_fp8((int)(r).x, true);  \
  f32x2 d2 = __builtin_amdgcn_cvt_pk_f32_fp8((int)(r).y, false); \
  f32x2 d3 = __builtin_amdgcn_cvt_pk_f32_fp8((int)(r).y, true);  \
  f32x2 d4 = __builtin_amdgcn_cvt_pk_f32_fp8((int)(r).z, false); \
  f32x2 d5 = __builtin_amdgcn_cvt_pk_f32_fp8((int)(r).z, true);  \
  f32x2 d6 = __builtin_amdgcn_cvt_pk_f32_fp8((int)(r).w, false); \
  f32x2 d7 = __builtin_amdgcn_cvt_pk_f32_fp8((int)(r).w, true);  \
  dst[0] = d0[0]; dst[1] = d0[1]; dst[2] = d1[0]; dst[3] = d1[1]; \
  dst[4] = d2[0]; dst[5] = d2[1]; dst[6] = d3[0]; dst[7] = d3[1]; \
  dst[8] = d4[0]; dst[9] = d4[1]; dst[10] = d5[0]; dst[11] = d5[1]; \
  dst[12] = d6[0]; dst[13] = d6[1]; dst[14] = d7[0]; dst[15] = d7[1]; }

// radix pass A + weight-convert riders
__global__ __launch_bounds__(256) void k_histA(const int* __restrict__ dst,
                                               int* __restrict__ histmat,
                                               int E, int NB,
                                               const float* __restrict__ W1,
                                               bf16_t* __restrict__ w1t,
                                               const float* __restrict__ W2,
                                               bf16_t* __restrict__ w2t) {
  if (blockIdx.x >= NCHUNK) {
    int i = (blockIdx.x - NCHUNK) * 256 + threadIdx.x;
    if (i < FIN * FH) {
      int c = i >> 9, k = i & 511;
      w1t[i] = (bf16_t)W1[(size_t)k * FH + c];
    }
    if (i < FH * FO) {
      int c = i >> 6, k = i & 63;
      w2t[i] = (bf16_t)W2[(size_t)k * FO + c];
    }
    return;
  }
  __shared__ int lh[NBMAX];
  int t = threadIdx.x;
  int g = blockIdx.x;
  for (int i = t; i < NB; i += 256) lh[i] = 0;
  __syncthreads();
  int C = (E + NCHUNK - 1) / NCHUNK;
  int e0 = g * C, e1 = min(E, e0 + C);
  for (int e = e0 + t; e < e1; e += 256) {
    atomicAdd(&lh[dst[e] >> BSH], 1);
  }
  __syncthreads();
  for (int b = t; b < NB; b += 256) histmat[(size_t)b * NCHUNK + g] = lh[b];
}

// radix pass B: per-bucket exclusive scan over chunks -> rowscan, total -> rowsum
__global__ __launch_bounds__(256) void k_scanB(const int* __restrict__ histmat,
                                               int* __restrict__ rowscan,
                                               int* __restrict__ rowsum, int NB) {
  __shared__ int s[NCHUNK];
  int b = blockIdx.x;
  int t = threadIdx.x;
  int v = histmat[(size_t)b * NCHUNK + t];
  s[t] = v;
  __syncthreads();
  #pragma unroll
  for (int off = 1; off < NCHUNK; off <<= 1) {
    int tmp = (t >= off) ? s[t - off] : 0;
    __syncthreads();
    s[t] += tmp;
    __syncthreads();
  }
  rowscan[(size_t)b * NCHUNK + t] = s[t] - v;
  if (t == 255) rowsum[b] = s[255];
}

// radix pass C: scatter packed (dlocal<<23 | src) into bucket-grouped part[]
__global__ __launch_bounds__(256) void k_scatC(const int* __restrict__ ei,
                                               const int* __restrict__ rowscan,
                                               const int* __restrict__ rowsum,
                                               unsigned* __restrict__ part,
                                               int E, int NB) {
  __shared__ int lcur[NBMAX];
  __shared__ int sc[256];
  int t = threadIdx.x;
  int g = blockIdx.x;
  int carry = 0;
  for (int bb = 0; bb < NB; bb += 256) {
    int idx = bb + t;
    int v = (idx < NB) ? rowsum[idx] : 0;
    sc[t] = v;
    __syncthreads();
    #pragma unroll
    for (int off = 1; off < 256; off <<= 1) {
      int tmp = (t >= off) ? sc[t - off] : 0;
      __syncthreads();
      sc[t] += tmp;
      __syncthreads();
    }
    if (idx < NB) lcur[idx] = sc[t] - v + carry + rowscan[(size_t)idx * NCHUNK + g];
    carry += sc[255];
    __syncthreads();
  }
  __syncthreads();
  int C = (E + NCHUNK - 1) / NCHUNK;
  int e0 = g * C, e1 = min(E, e0 + C);
  for (int e = e0 + t; e < e1; e += 256) {
    int s = ei[e];
    int d = ei[E + e];
    int b = d >> BSH;
    int pos = atomicAdd(&lcur[b], 1);
    part[pos] = (unsigned)s | ((unsigned)(d & (BNODES - 1)) << 23);
  }
}

// per-bucket CSR build; writes csr (node-sorted), rowoff, dinv
__global__ __launch_bounds__(256) void k_csrb(const unsigned* __restrict__ part,
                                              const int* __restrict__ rowsum,
                                              int* __restrict__ csr,
                                              int* __restrict__ rowoff,
                                              float* __restrict__ dinv,
                                              int n, int NB) {
  __shared__ int sc[256];
  __shared__ int lhist[BNODES];
  __shared__ int lro[BNODES];
  __shared__ int lcur[BNODES];
  __shared__ int lcsr[BCAP];
  int b = blockIdx.x;
  int t = threadIdx.x;
  int base = b << BSH;

  // bo = sum(rowsum[0..b))
  int partial = 0;
  for (int i = t; i < b; i += 256) partial += rowsum[i];
  sc[t] = partial;
  __syncthreads();
  #pragma unroll
  for (int off = 128; off > 0; off >>= 1) {
    if (t < off) sc[t] += sc[t + off];
    __syncthreads();
  }
  int bo = sc[0];
  int cnt = rowsum[b];
  __syncthreads();

  lhist[t] = 0;
  __syncthreads();
  const unsigned* pp = part + bo;
  for (int j = t; j < cnt; j += 256) atomicAdd(&lhist[pp[j] >> 23], 1);
  __syncthreads();

  int v0 = lhist[t];
  sc[t] = v0;
  __syncthreads();
  #pragma unroll
  for (int off = 1; off < 256; off <<= 1) {
    int tmp = (t >= off) ? sc[t - off] : 0;
    __syncthreads();
    sc[t] += tmp;
    __syncthreads();
  }
  lro[t] = sc[t] - v0;
  __syncthreads();

  {
    int v = base + t;
    if (v < n) {
      rowoff[v] = bo + lro[t];
      dinv[v] = rsqrtf((float)(lhist[t] + 1));
    }
    lcur[t] = 0;
    if (t == 0 && base + BNODES >= n) rowoff[n] = bo + cnt;
  }
  __syncthreads();

  if (cnt <= BCAP) {
    for (int j = t; j < cnt; j += 256) {
      unsigned pk = pp[j];
      int dl = (int)(pk >> 23);
      int pos = atomicAdd(&lcur[dl], 1);
      lcsr[lro[dl] + pos] = (int)(pk & 0x7FFFFFu);
    }
    __syncthreads();
    for (int j = t; j < cnt; j += 256) csr[bo + j] = lcsr[j];
  } else {
    for (int j = t; j < cnt; j += 256) {
      unsigned pk = pp[j];
      int dl = (int)(pk >> 23);
      int pos = atomicAdd(&lcur[dl], 1);
      csr[bo + lro[dl] + pos] = (int)(pk & 0x7FFFFFu);
    }
  }
}

// GEMM1 via MFMA: P1[n][64] (fp8 e4m3) = dinv[n] * (x[n] @ W1)
__global__ __launch_bounds__(256) void k_gemm1(const float* __restrict__ x,
                                               const bf16_t* __restrict__ w1t,
                                               const float* __restrict__ dinv,
                                               unsigned char* __restrict__ P1, int n) {
  int t = threadIdx.x;
  int w = t >> 6, l = t & 63;
  int rowBase = blockIdx.x * 64 + w * 16;
  int fr = l & 15, fk = l >> 4;
  int ar = rowBase + fr; if (ar >= n) ar = n - 1;
  const float* xp = x + (size_t)ar * FIN + fk * 8;
  const bf16_t* wb = w1t + (size_t)fr * FIN + fk * 8;

  f32x4 acc0 = {0.f, 0.f, 0.f, 0.f};
  f32x4 acc1 = {0.f, 0.f, 0.f, 0.f};
  f32x4 acc2 = {0.f, 0.f, 0.f, 0.f};
  f32x4 acc3 = {0.f, 0.f, 0.f, 0.f};

  #pragma unroll 4
  for (int kt = 0; kt < FIN; kt += 32) {
    float4 a0 = *(const float4*)(xp + kt);
    float4 a1 = *(const float4*)(xp + kt + 4);
    bf16x8 av;
    av[0] = (bf16_t)a0.x; av[1] = (bf16_t)a0.y; av[2] = (bf16_t)a0.z; av[3] = (bf16_t)a0.w;
    av[4] = (bf16_t)a1.x; av[5] = (bf16_t)a1.y; av[6] = (bf16_t)a1.z; av[7] = (bf16_t)a1.w;
    bf16x8 b0 = *(const bf16x8*)(wb + kt);
    bf16x8 b1 = *(const bf16x8*)(wb + (size_t)16 * FIN + kt);
    bf16x8 b2 = *(const bf16x8*)(wb + (size_t)32 * FIN + kt);
    bf16x8 b3 = *(const bf16x8*)(wb + (size_t)48 * FIN + kt);
    acc0 = __builtin_amdgcn_mfma_f32_16x16x32_bf16(av, b0, acc0, 0, 0, 0);
    acc1 = __builtin_amdgcn_mfma_f32_16x16x32_bf16(av, b1, acc1, 0, 0, 0);
    acc2 = __builtin_amdgcn_mfma_f32_16x16x32_bf16(av, b2, acc2, 0, 0, 0);
    acc3 = __builtin_amdgcn_mfma_f32_16x16x32_bf16(av, b3, acc3, 0, 0, 0);
  }

  #pragma unroll
  for (int rg = 0; rg < 4; rg++) {
    int grow = rowBase + fk * 4 + rg;
    if (grow < n) {
      float dv = dinv[grow];
      unsigned char* prow = P1 + (size_t)grow * FH + fr;
      prow[0]  = f32_to_fp8(dv * acc0[rg]);
      prow[16] = f32_to_fp8(dv * acc1[rg]);
      prow[32] = f32_to_fp8(dv * acc2[rg]);
      prow[48] = f32_to_fp8(dv * acc3[rg]);
    }
  }
}

// FUSED gather1 + gemm2: block = 64 nodes (4 waves x 16).
__global__ __launch_bounds__(256) void k_g1g2(const unsigned char* __restrict__ P1,
                                              const int* __restrict__ csr,
                                              const int* __restrict__ rowoff,
                                              const float* __restrict__ dinv,
                                              const float* __restrict__ b1,
                                              const bf16_t* __restrict__ w2t,
                                              unsigned char* __restrict__ P2, int n) {
  __shared__ bf16_t hl[64][72];
  int t = threadIdx.x;
  int w = t >> 6, l = t & 63;
  int sg = l >> 2, dg = l & 3;      // lane covers dims dg*16..dg*16+15
  int nl = w * 16 + sg;             // node-local 0..63
  int v = blockIdx.x * 64 + nl;
  bool act = v < n;

  bf16x8 hv0 = {};
  bf16x8 hv1 = {};
  if (act) {
    const uint4* P1v = (const uint4*)P1;
    int base = rowoff[v];
    int cnt = rowoff[v + 1] - base;
    float a[16], c[16];
    {
      uint4 r = P1v[(size_t)v * 4 + dg];  // self loop
      SET16(a, r);
      #pragma unroll
      for (int k = 0; k < 16; k++) c[k] = 0.f;
    }
    int cnt4 = cnt & ~3;
    int j = 0;
    for (; j < cnt4; j += 4) {
      int u0 = csr[base + j];
      int u1 = csr[base + j + 1];
      int u2 = csr[base + j + 2];
      int u3 = csr[base + j + 3];
      uint4 r0 = P1v[(size_t)u0 * 4 + dg];
      uint4 r1 = P1v[(size_t)u1 * 4 + dg];
      uint4 r2 = P1v[(size_t)u2 * 4 + dg];
      uint4 r3 = P1v[(size_t)u3 * 4 + dg];
      ACC16(a, r0);
      ACC16(c, r1);
      ACC16(a, r2);
      ACC16(c, r3);
    }
    for (; j < cnt; j++) {
      int u = csr[base + j];
      uint4 r = P1v[(size_t)u * 4 + dg];
      ACC16(a, r);
    }
    float dv = dinv[v];
    const float4* b1v = (const float4*)b1;
    #pragma unroll
    for (int q = 0; q < 4; q++) {
      float4 bb = b1v[dg * 4 + q];
      float s0 = fmaxf(dv * (a[q*4+0] + c[q*4+0]) + bb.x, 0.f);
      float s1 = fmaxf(dv * (a[q*4+1] + c[q*4+1]) + bb.y, 0.f);
      float s2 = fmaxf(dv * (a[q*4+2] + c[q*4+2]) + bb.z, 0.f);
      float s3 = fmaxf(dv * (a[q*4+3] + c[q*4+3]) + bb.w, 0.f);
      if (q < 2) {
        hv0[q*4+0] = (bf16_t)s0; hv0[q*4+1] = (bf16_t)s1;
        hv0[q*4+2] = (bf16_t)s2; hv0[q*4+3] = (bf16_t)s3;
      } else {
        hv1[(q-2)*4+0] = (bf16_t)s0; hv1[(q-2)*4+1] = (bf16_t)s1;
        hv1[(q-2)*4+2] = (bf16_t)s2; hv1[(q-2)*4+3] = (bf16_t)s3;
      }
    }
  }
  *(bf16x8*)&hl[nl][dg * 16]     = hv0;
  *(bf16x8*)&hl[nl][dg * 16 + 8] = hv1;
  __syncthreads();

  // gemm2 from LDS: wave w handles local rows w*16..w*16+15
  int fr = l & 15, fk = l >> 4;
  f32x4 acc0 = {0.f, 0.f, 0.f, 0.f};
  f32x4 acc1 = {0.f, 0.f, 0.f, 0.f};
  const bf16_t* wb0 = w2t + (size_t)fr * FH + fk * 8;
  const bf16_t* wb1 = w2t + (size_t)(fr + 16) * FH + fk * 8;
  #pragma unroll
  for (int kt = 0; kt < FH; kt += 32) {
    bf16x8 af = *(const bf16x8*)&hl[w * 16 + fr][kt + fk * 8];
    bf16x8 b0 = *(const bf16x8*)(wb0 + kt);
    bf16x8 b1v_ = *(const bf16x8*)(wb1 + kt);
    acc0 = __builtin_amdgcn_mfma_f32_16x16x32_bf16(af, b0, acc0, 0, 0, 0);
    acc1 = __builtin_amdgcn_mfma_f32_16x16x32_bf16(af, b1v_, acc1, 0, 0, 0);
  }
  #pragma unroll
  for (int rg = 0; rg < 4; rg++) {
    int grow = blockIdx.x * 64 + w * 16 + fk * 4 + rg;
    if (grow < n) {
      float dv = dinv[grow];
      unsigned char* prow = P2 + (size_t)grow * FO + fr;
      prow[0]  = f32_to_fp8(dv * acc0[rg]);
      prow[16] = f32_to_fp8(dv * acc1[rg]);
    }
  }
}

// gather2 + bias + log_softmax (fp8 rows, 32B): wave = 32 subgroups x 2 lanes.
__global__ __launch_bounds__(256) void k_g2final(const unsigned char* __restrict__ P2,
                                                 const int* __restrict__ csr,
                                                 const int* __restrict__ rowoff,
                                                 const float* __restrict__ dinv,
                                                 const float* __restrict__ b2,
                                                 float* __restrict__ out, int n) {
  int l = threadIdx.x & 63;
  int sg = l >> 1, dg = l & 1;   // lane covers dims dg*16 .. dg*16+15
  int wv = (blockIdx.x * 256 + threadIdx.x) >> 6;
  int v = wv * 32 + sg;
  if (v >= n) return;
  const uint4* P2v = (const uint4*)P2;  // row = 2 x uint4
  int base = rowoff[v];
  int cnt = rowoff[v + 1] - base;

  float a[16], c[16];
  {
    uint4 r = P2v[(size_t)v * 2 + dg];  // self loop
    SET16(a, r);
    #pragma unroll
    for (int k = 0; k < 16; k++) c[k] = 0.f;
  }

  int cnt4 = cnt & ~3;
  int j = 0;
  for (; j < cnt4; j += 4) {
    int u0 = csr[base + j];
    int u1 = csr[base + j + 1];
    int u2 = csr[base + j + 2];
    int u3 = csr[base + j + 3];
    uint4 r0 = P2v[(size_t)u0 * 2 + dg];
    uint4 r1 = P2v[(size_t)u1 * 2 + dg];
    uint4 r2 = P2v[(size_t)u2 * 2 + dg];
    uint4 r3 = P2v[(size_t)u3 * 2 + dg];
    ACC16(a, r0);
    ACC16(c, r1);
    ACC16(a, r2);
    ACC16(c, r3);
  }
  for (; j < cnt; j++) {
    int u = csr[base + j];
    uint4 r = P2v[(size_t)u * 2 + dg];
    ACC16(a, r);
  }

  float dv = dinv[v];
  const float4* b2v = (const float4*)b2;
  float val[16];
  #pragma unroll
  for (int q = 0; q < 4; q++) {
    float4 bb = b2v[dg * 4 + q];
    val[q*4+0] = dv * (a[q*4+0] + c[q*4+0]) + bb.x;
    val[q*4+1] = dv * (a[q*4+1] + c[q*4+1]) + bb.y;
    val[q*4+2] = dv * (a[q*4+2] + c[q*4+2]) + bb.z;
    val[q*4+3] = dv * (a[q*4+3] + c[q*4+3]) + bb.w;
  }
  float m = val[0];
  #pragma unroll
  for (int q = 1; q < 16; q++) m = fmaxf(m, val[q]);
  m = fmaxf(m, __shfl_xor(m, 1, 64));
  float se = 0.f;
  #pragma unroll
  for (int q = 0; q < 16; q++) se += expf(val[q] - m);
  se += __shfl_xor(se, 1, 64);
  float lse = m + logf(se);
  float* orow = out + (size_t)v * FO + dg * 16;
  #pragma unroll
  for (int q = 0; q < 4; q++) {
    float4 o;
    o.x = val[q*4+0] - lse; o.y = val[q*4+1] - lse;
    o.z = val[q*4+2] - lse; o.w = val[q*4+3] - lse;
    *(float4*)(orow + q * 4) = o;
  }
}

extern "C" void kernel_launch(void* const* d_in, const int* in_sizes, int n_in,
                              void* d_out, int out_size, void* d_ws, size_t ws_size,
                              hipStream_t stream) {
  const float* x  = (const float*)d_in[0];
  const int*   ei = (const int*)d_in[1];
  const float* W1 = (const float*)d_in[2];
  const float* b1 = (const float*)d_in[3];
  const float* W2 = (const float*)d_in[4];
  const float* b2 = (const float*)d_in[5];
  const int N = in_sizes[0] / FIN;
  const int E = in_sizes[1] / 2;
  float* out = (float*)d_out;

  size_t NP = ((size_t)N + 63) & ~(size_t)63;
  size_t EP = ((size_t)E + 63) & ~(size_t)63;
  int NB = (N + BNODES - 1) >> BSH;

  int*           histmat = (int*)d_ws;                        // NBMAX*NCHUNK
  int*           rowscan = histmat + (size_t)NBMAX * NCHUNK;  // NBMAX*NCHUNK
  int*           rowsum  = rowscan + (size_t)NBMAX * NCHUNK;  // NBMAX
  int*           rowoff  = rowsum + NBMAX;                    // NP+64 (incl sentinel)
  float*         dinv    = (float*)(rowoff + NP + 64);        // NP
  int*           csr     = (int*)(dinv + NP);                 // EP
  unsigned*      part    = (unsigned*)(csr + EP);             // EP
  bf16_t*        w1t     = (bf16_t*)(part + EP);              // 64*512
  bf16_t*        w2t     = w1t + (size_t)FH * FIN;            // 32*64
  unsigned char* P1      = (unsigned char*)(w2t + (size_t)FO * FH);  // NP*64 bytes
  unsigned char* P2      = P1 + NP * FH;                      // NP*32 bytes

  int wconvB = (FIN * FH + 255) / 256;  // 128 rider blocks
  k_histA<<<NCHUNK + wconvB, 256, 0, stream>>>(ei + E, histmat, E, NB, W1, w1t, W2, w2t);
  k_scanB<<<NB, 256, 0, stream>>>(histmat, rowscan, rowsum, NB);
  k_scatC<<<NCHUNK, 256, 0, stream>>>(ei, rowscan, rowsum, part, E, NB);
  k_csrb<<<NB, 256, 0, stream>>>(part, rowsum, csr, rowoff, dinv, N, NB);
  k_gemm1<<<(N + 63) / 64, 256, 0, stream>>>(x, w1t, dinv, P1, N);
  k_g1g2<<<(N + 63) / 64, 256, 0, stream>>>(P1, csr, rowoff, dinv, b1, w2t, P2, N);
  {
    int waves = (N + 31) / 32;
    k_g2final<<<(waves + 3) / 4, 256, 0, stream>>>(P2, csr, rowoff, dinv, b2, out, N);
  }
}